// Round 7
// baseline (2566.327 us; speedup 1.0000x reference)
//
#include <hip/hip_runtime.h>

#define NN 2048      // points
#define NB 16        // batch
#define KK 20        // k neighbors
#define EPSF 1e-5f

typedef unsigned long long ull;
typedef _Float16 v8h __attribute__((ext_vector_type(8)));
typedef _Float16 v4h __attribute__((ext_vector_type(4)));
typedef float v4f __attribute__((ext_vector_type(4)));

__device__ __forceinline__ float shflx_f(float v, int m) { return __shfl_xor(v, m, 64); }
__device__ __forceinline__ ull shflx_u64(ull v, int m) {
  int lo = __shfl_xor((int)(unsigned)v, m, 64);
  int hi = __shfl_xor((int)(unsigned)(v >> 32), m, 64);
  return (((ull)(unsigned)hi) << 32) | (unsigned)lo;
}
__device__ __forceinline__ ull packkey(float s, int n) {
  unsigned u = __float_as_uint(s);
  u = (u & 0x80000000u) ? ~u : (u | 0x80000000u);
  return (((ull)u) << 32) | (unsigned)(2047 - n);   // ties -> lowest index wins under max
}

// ---------------- prep (layer 1 only): fp32 [C][N] -> f16 hi/lo [n][Cp] + xx ----
__global__ __launch_bounds__(256) void prep_kernel(const float* __restrict__ x,
    _Float16* __restrict__ xh, _Float16* __restrict__ xl, float* __restrict__ xx,
    int C, int KB, long bstride)
{
  const int b = blockIdx.y;
  const int n = blockIdx.x * 256 + threadIdx.x;
  const float* xb = x + (size_t)b * bstride;
  const int Cp = KB * 32;
  _Float16* ph = xh + ((size_t)b * NN + n) * Cp;
  _Float16* pl = xl + ((size_t)b * NN + n) * Cp;
  float s = 0.f;
  for (int kb = 0; kb < KB; kb++) {
    for (int g = 0; g < 4; g++) {
      v8h hv, lv;
#pragma unroll
      for (int j = 0; j < 8; j++) {
        int c = kb * 32 + g * 8 + j;
        float v = (c < C) ? xb[(size_t)c * NN + n] : 0.f;
        _Float16 h = (_Float16)v;
        hv[j] = h;
        lv[j] = (_Float16)(v - (float)h);
        s = fmaf(v, v, s);
      }
      *(v8h*)(ph + kb * 32 + g * 8) = hv;
      *(v8h*)(pl + kb * 32 + g * 8) = lv;
    }
  }
  xx[b * NN + n] = s;
}

// ---------------- tile scorer: 64 queries (4 A-tiles) x 16 candidates ----------
template<int KB>
__device__ __forceinline__ void tile_scores(const v8h (&Bh)[KB], const v8h (&Bl)[KB],
    const v8h (&Ah)[4][KB], const v8h (&Al)[4][KB], float xv, v4f (&out)[4])
{
#pragma unroll
  for (int a = 0; a < 4; a++) {
    v4f a0 = {0.f, 0.f, 0.f, 0.f};
    v4f a1 = {0.f, 0.f, 0.f, 0.f};
#pragma unroll
    for (int kb = 0; kb < KB; kb++) {
      v4f& acc = (kb & 1) ? a1 : a0;
      acc = __builtin_amdgcn_mfma_f32_16x16x32_f16(Ah[a][kb], Bh[kb], acc, 0, 0, 0);
      acc = __builtin_amdgcn_mfma_f32_16x16x32_f16(Ah[a][kb], Bl[kb], acc, 0, 0, 0);
      acc = __builtin_amdgcn_mfma_f32_16x16x32_f16(Al[a][kb], Bh[kb], acc, 0, 0, 0);
    }
    v4f s = a0 + a1;
#pragma unroll
    for (int j = 0; j < 4; j++) out[a][j] = s[j] - 0.5f * xv;
  }
}

// ---------------- kNN stage 1: 4-deep B prefetch ring, two passes -------------
template<int KB>
__global__ __launch_bounds__(256, 1) void knn2(
    const _Float16* __restrict__ xh, const _Float16* __restrict__ xl,
    const float* __restrict__ xxg, ull* __restrict__ slistG, int* __restrict__ cntG)
{
  __shared__ float gmL[256][33];
  __shared__ float tauL[256];
  __shared__ int scnt[256];

  const int t = threadIdx.x;
  const int lane = t & 63;
  const int wave = t >> 6;
  const int col = lane & 15;
  const int quad = lane >> 4;
  const int quad8 = quad * 8;
  const int b = blockIdx.x >> 1;
  const int chunk = blockIdx.x & 1;
  const int qg = blockIdx.y;
  const int Cp = KB * 32;
  const int cb = chunk * 1024;
  const _Float16* xhb = xh + (size_t)b * NN * Cp;
  const _Float16* xlb = xl + (size_t)b * NN * Cp;
  const float* xxb = xxg + b * NN;

  v8h Ah[4][KB], Al[4][KB];
  const int qw = qg * 256 + wave * 64;
#pragma unroll
  for (int a = 0; a < 4; a++) {
    const _Float16* pa = xhb + (size_t)(qw + a * 16 + col) * Cp + quad8;
    const _Float16* pb = xlb + (size_t)(qw + a * 16 + col) * Cp + quad8;
#pragma unroll
    for (int kb = 0; kb < KB; kb++) {
      Ah[a][kb] = *(const v8h*)(pa + kb * 32);
      Al[a][kb] = *(const v8h*)(pb + kb * 32);
    }
  }

  v8h Bh[4][KB], Bl[4][KB];
  float xvb[4];
  auto loadB = [&](int slot, int tt) {
    int t2 = tt < 63 ? tt : 63;
    int n = cb + t2 * 16 + col;
    const _Float16* pb = xhb + (size_t)n * Cp + quad8;
    const _Float16* pl = xlb + (size_t)n * Cp + quad8;
#pragma unroll
    for (int kb = 0; kb < KB; kb++) {
      Bh[slot][kb] = *(const v8h*)(pb + kb * 32);
      Bl[slot][kb] = *(const v8h*)(pl + kb * 32);
    }
    xvb[slot] = xxb[n];
  };

  // ---- pass 1: group maxima (16 cols x 2 tile-parities = 32 groups/query) ----
  float gm[4][8];
#pragma unroll
  for (int a = 0; a < 4; a++)
#pragma unroll
    for (int j = 0; j < 8; j++) gm[a][j] = -3.4e38f;

#pragma unroll
  for (int s = 0; s < 4; s++) loadB(s, s);
  for (int tt = 0; tt < 64; tt += 4) {
#pragma unroll
    for (int s = 0; s < 4; s++) {
      v4f out[4];
      tile_scores<KB>(Bh[s], Bl[s], Ah, Al, xvb[s], out);
      loadB(s, tt + 4 + s);
      const int par = s & 1;
#pragma unroll
      for (int a = 0; a < 4; a++)
#pragma unroll
        for (int j = 0; j < 4; j++) gm[a][j * 2 + par] = fmaxf(gm[a][j * 2 + par], out[a][j]);
    }
  }

#pragma unroll
  for (int a = 0; a < 4; a++)
#pragma unroll
    for (int j = 0; j < 4; j++) {
      int qi = wave * 64 + a * 16 + quad * 4 + j;
      gmL[qi][col * 2 + 0] = gm[a][j * 2 + 0];
      gmL[qi][col * 2 + 1] = gm[a][j * 2 + 1];
    }
  scnt[t] = 0;
  asm volatile("s_waitcnt lgkmcnt(0)" ::: "memory");

  // tau = rank-19 of 32 group maxima (provably <= true 20th score)
  for (int r = 0; r < 32; r++) {
    const int q = wave * 64 + r * 2 + (lane >> 5);
    const int idx = lane & 31;
    float v = gmL[q][idx];
#pragma unroll
    for (int kk = 2; kk <= 32; kk <<= 1) {
#pragma unroll
      for (int m = kk >> 1; m >= 1; m >>= 1) {
        float o = shflx_f(v, m);
        bool keepmax = ((idx & kk) == 0) == ((idx & m) == 0);
        v = keepmax ? fmaxf(v, o) : fminf(v, o);
      }
    }
    if (idx == 19) tauL[q] = v;
  }
  asm volatile("s_waitcnt lgkmcnt(0)" ::: "memory");

  float tq[4][4];
#pragma unroll
  for (int a = 0; a < 4; a++)
#pragma unroll
    for (int j = 0; j < 4; j++) tq[a][j] = tauL[wave * 64 + a * 16 + quad * 4 + j];

  // ---- pass 2: bitwise-identical rescore, compact survivors >= tau ----
  ull* slB = slistG + (((size_t)b * NN + qg * 256) * 2 + chunk) * 64;
#pragma unroll
  for (int s = 0; s < 4; s++) loadB(s, s);
  for (int tt = 0; tt < 64; tt += 4) {
#pragma unroll
    for (int s = 0; s < 4; s++) {
      v4f out[4];
      tile_scores<KB>(Bh[s], Bl[s], Ah, Al, xvb[s], out);
      loadB(s, tt + 4 + s);
      int n = cb + (tt + s) * 16 + col;
#pragma unroll
      for (int a = 0; a < 4; a++)
#pragma unroll
        for (int j = 0; j < 4; j++) {
          float sc = out[a][j];
          if (sc >= tq[a][j]) {
            int qi = wave * 64 + a * 16 + quad * 4 + j;
            int pos = atomicAdd(&scnt[qi], 1);
            if (pos < 64) slB[(size_t)qi * 128 + pos] = packkey(sc, n);
          }
        }
    }
  }
  asm volatile("s_waitcnt lgkmcnt(0)" ::: "memory");
  cntG[((size_t)b * NN + qg * 256 + t) * 2 + chunk] = scnt[t];
}

// ---------------- kNN stage 2: merge 2 chunk survivor lists -> top-20 --------
__global__ __launch_bounds__(256) void knn_merge(const ull* __restrict__ slistG,
    const int* __restrict__ cntG, const _Float16* __restrict__ xh,
    const _Float16* __restrict__ xl, const float* __restrict__ xxg,
    int* __restrict__ idxout, int Cp, int C)
{
  const int lane = threadIdx.x & 63, wave = threadIdx.x >> 6;
  const int b = blockIdx.y;
  const int q = blockIdx.x * 4 + wave;
  const int c0 = cntG[((size_t)b * NN + q) * 2 + 0];
  const int c1 = cntG[((size_t)b * NN + q) * 2 + 1];
  int* op = idxout + ((size_t)b * NN + q) * KK;

  if (c0 <= 64 && c1 <= 64) {
    const ull* s0 = slistG + ((size_t)b * NN + q) * 128;
    const int total = c0 + c1;
    ull e0 = 0, e1 = 0;
    int p0 = lane, p1 = lane + 64;
    if (p0 < total) e0 = (p0 < c0) ? s0[p0] : s0[64 + p0 - c0];
    if (p1 < total) e1 = (p1 < c0) ? s0[p1] : s0[64 + p1 - c0];
    for (int s = 0; s < KK; s++) {
      ull m = e0 > e1 ? e0 : e1;
      ull g = m;
#pragma unroll
      for (int d = 1; d < 64; d <<= 1) { ull o = shflx_u64(g, d); g = o > g ? o : g; }
      if (lane == 0) op[s] = 2047 - (int)(g & 0xFFFFFFFFu);
      if (e0 == g) e0 = 0; else if (e1 == g) e1 = 0;
    }
  } else {
    // exact fallback (survivor cap overflow — expected never): full fp32 rescan
    const _Float16* qh = xh + ((size_t)b * NN + q) * Cp;
    const _Float16* ql = xl + ((size_t)b * NN + q) * Cp;
    const float* xxb = xxg + b * NN;
    float sc[32];
#pragma unroll
    for (int i = 0; i < 32; i++) sc[i] = -0.5f * xxb[lane + 64 * i];
    for (int c = 0; c < C; c++) {
      float qv = (float)qh[c] + (float)ql[c];
      for (int i = 0; i < 32; i++) {
        int n = lane + 64 * i;
        float bv = (float)xh[((size_t)b * NN + n) * Cp + c] + (float)xl[((size_t)b * NN + n) * Cp + c];
        sc[i] = fmaf(qv, bv, sc[i]);
      }
    }
    for (int s = 0; s < KK; s++) {
      ull m = 0; int mi = -1;
      for (int i = 0; i < 32; i++) {
        ull k = packkey(sc[i], lane + 64 * i);
        if (k > m) { m = k; mi = i; }
      }
      ull g = m;
#pragma unroll
      for (int d = 1; d < 64; d <<= 1) { ull o = shflx_u64(g, d); g = o > g ? o : g; }
      if (lane == 0) op[s] = 2047 - (int)(g & 0xFFFFFFFFu);
      if (m == g && mi >= 0) sc[mi] = -3.4e38f;
    }
  }
}

// ---------------- per-layer setup: idx histogram (+xx zero) and weight convert --
__global__ __launch_bounds__(256) void setup_kernel(const int* __restrict__ idx,
    int* __restrict__ cnt, const float* __restrict__ w,
    _Float16* __restrict__ wuh, _Float16* __restrict__ wul,
    _Float16* __restrict__ wvh, _Float16* __restrict__ wvl,
    int C, int Cp, int O, float* __restrict__ xx, int zxx)
{
  __shared__ int h[2048];
  const int blk = blockIdx.x, t = threadIdx.x;
  if (blk < NB) {
    const int b = blk;
    for (int i = t; i < 2048; i += 256) h[i] = 0;
    if (zxx) for (int i = t; i < 2048; i += 256) xx[b * 2048 + i] = 0.f;
    __syncthreads();
    const int* ib = idx + (size_t)b * NN * KK;
    for (int i = t; i < NN * KK; i += 256) atomicAdd(&h[ib[i]], 1);
    __syncthreads();
    for (int i = t; i < 2048; i += 256) cnt[b * 2048 + i] = h[i];
  } else {
    int e = (blk - NB) * 256 + t;
    if (e < O * Cp) {
      int o = e / Cp, c = e - o * Cp;
      float a = 0.f, bv = 0.f;
      if (c < C) { a = w[o * 2 * C + c]; bv = w[o * 2 * C + C + c]; }
      float v = bv - a;
      _Float16 ah = (_Float16)a; wuh[e] = ah; wul[e] = (_Float16)(a - (float)ah);
      _Float16 vh = (_Float16)v; wvh[e] = vh; wvl[e] = (_Float16)(v - (float)vh);
    }
  }
}

__global__ __launch_bounds__(256) void w5cvt(const float* __restrict__ w5,
    _Float16* __restrict__ w5h, _Float16* __restrict__ w5l)
{
  int idx = blockIdx.x * 256 + threadIdx.x;
  float v = w5[idx];
  _Float16 h = (_Float16)v;
  w5h[idx] = h;
  w5l[idx] = (_Float16)(v - (float)h);
}

// ---------------- U/V chunk via MFMA: U = Wa*x, V = (Wb-Wa)*x -----------------
__global__ __launch_bounds__(256) void uv_mfma(const _Float16* __restrict__ wuh,
    const _Float16* __restrict__ wul, const _Float16* __restrict__ wvh,
    const _Float16* __restrict__ wvl, const _Float16* __restrict__ xh,
    const _Float16* __restrict__ xl, float* __restrict__ Uo, float* __restrict__ Vo,
    int Cp, int Och)
{
  const int lane = threadIdx.x & 63, wave = threadIdx.x >> 6;
  const int col = lane & 15, quad = lane >> 4, quad8 = quad * 8;
  const int b = blockIdx.z;
  const int o0 = blockIdx.x * 32;
  const int nb0 = blockIdx.y * 512 + wave * 128;
  v4f aU[2][8], aV[2][8];
#pragma unroll
  for (int a = 0; a < 2; a++)
#pragma unroll
    for (int t = 0; t < 8; t++) { aU[a][t] = {0.f,0.f,0.f,0.f}; aV[a][t] = {0.f,0.f,0.f,0.f}; }

  const int KBr = Cp >> 5;
  for (int kb = 0; kb < KBr; kb++) {
    v8h Uh[2], Ul[2], Vh[2], Vl[2];
#pragma unroll
    for (int a = 0; a < 2; a++) {
      size_t off = (size_t)(o0 + a * 16 + col) * Cp + kb * 32 + quad8;
      Uh[a] = *(const v8h*)(wuh + off);
      Ul[a] = *(const v8h*)(wul + off);
      Vh[a] = *(const v8h*)(wvh + off);
      Vl[a] = *(const v8h*)(wvl + off);
    }
#pragma unroll
    for (int t = 0; t < 8; t++) {
      int n = nb0 + t * 16 + col;
      size_t boff = ((size_t)b * NN + n) * Cp + kb * 32 + quad8;
      v8h Bh = *(const v8h*)(xh + boff);
      v8h Bl = *(const v8h*)(xl + boff);
#pragma unroll
      for (int a = 0; a < 2; a++) {
        aU[a][t] = __builtin_amdgcn_mfma_f32_16x16x32_f16(Uh[a], Bh, aU[a][t], 0, 0, 0);
        aU[a][t] = __builtin_amdgcn_mfma_f32_16x16x32_f16(Uh[a], Bl, aU[a][t], 0, 0, 0);
        aU[a][t] = __builtin_amdgcn_mfma_f32_16x16x32_f16(Ul[a], Bh, aU[a][t], 0, 0, 0);
        aV[a][t] = __builtin_amdgcn_mfma_f32_16x16x32_f16(Vh[a], Bh, aV[a][t], 0, 0, 0);
        aV[a][t] = __builtin_amdgcn_mfma_f32_16x16x32_f16(Vh[a], Bl, aV[a][t], 0, 0, 0);
        aV[a][t] = __builtin_amdgcn_mfma_f32_16x16x32_f16(Vl[a], Bh, aV[a][t], 0, 0, 0);
      }
    }
  }
#pragma unroll
  for (int a = 0; a < 2; a++)
#pragma unroll
    for (int t = 0; t < 8; t++)
#pragma unroll
      for (int j = 0; j < 4; j++) {
        size_t base = ((size_t)b * Och + o0 + a * 16 + quad * 4 + j) * NN + nb0 + t * 16 + col;
        Uo[base] = aU[a][t][j];
        Vo[base] = aV[a][t][j];
      }
}

// ---------------- edge2: ONE gather pass + closed-form stats + frag output ----
// Stats: sumY = sG + K*sV ; sumY2 = sum_m cnt[m]*U[m]^2 + 2*sVG + K*sV2
// max_j y = V[n] + max_j U[idx[n,j]].  Output written directly as f16 hi/lo
// fragments for the next layer ([n][CpN]) and for y5 ([b][kc][n][32]); next
// layer's squared norms accumulated via atomics.
__global__ __launch_bounds__(256) void edge2(const float* __restrict__ U,
    const float* __restrict__ V, const int* __restrict__ idx,
    const int* __restrict__ cnt,
    _Float16* __restrict__ nxh, _Float16* __restrict__ nxl, int CpN,
    _Float16* __restrict__ y5h, _Float16* __restrict__ y5l, int gbase,
    float* __restrict__ xx, int Och)
{
  __shared__ float Ur[4 * 2052];
  __shared__ float red[20][4];
  __shared__ float smv[8];
  const int b = blockIdx.y, o0 = blockIdx.x * 4;
  const int t = threadIdx.x, lane = t & 63, wave = t >> 6;
  for (int r = 0; r < 4; r++)
    for (int i = t; i < NN; i += 256)
      Ur[r * 2052 + i] = U[((size_t)b * Och + o0 + r) * NN + i];
  __syncthreads();
  const float* Vp = V + ((size_t)b * Och + o0) * NN;
  const int* ib = idx + (size_t)b * NN * KK;
  const int* cb = cnt + b * NN;

  float sG[4] = {0,0,0,0}, sVG[4] = {0,0,0,0}, sV[4] = {0,0,0,0},
        sV2[4] = {0,0,0,0}, sU2[4] = {0,0,0,0};
  float Mr[4][8], Vr[4][8];
#pragma unroll
  for (int ni = 0; ni < 8; ni++) {
    const int n = t + ni * 256;
    const int* ip = ib + (size_t)n * KK;
    float G0 = 0, G1 = 0, G2 = 0, G3 = 0;
    float M0 = -3.4e38f, M1 = M0, M2 = M0, M3 = M0;
#pragma unroll
    for (int j = 0; j < KK; j++) {
      int m = ip[j];
      float u0 = Ur[m], u1 = Ur[2052 + m], u2 = Ur[4104 + m], u3 = Ur[6156 + m];
      G0 += u0; M0 = fmaxf(M0, u0);
      G1 += u1; M1 = fmaxf(M1, u1);
      G2 += u2; M2 = fmaxf(M2, u2);
      G3 += u3; M3 = fmaxf(M3, u3);
    }
    float v0 = Vp[n], v1 = Vp[NN + n], v2 = Vp[2 * NN + n], v3 = Vp[3 * NN + n];
    sG[0] += G0; sVG[0] = fmaf(v0, G0, sVG[0]); sV[0] += v0; sV2[0] = fmaf(v0, v0, sV2[0]);
    sG[1] += G1; sVG[1] = fmaf(v1, G1, sVG[1]); sV[1] += v1; sV2[1] = fmaf(v1, v1, sV2[1]);
    sG[2] += G2; sVG[2] = fmaf(v2, G2, sVG[2]); sV[2] += v2; sV2[2] = fmaf(v2, v2, sV2[2]);
    sG[3] += G3; sVG[3] = fmaf(v3, G3, sVG[3]); sV[3] += v3; sV2[3] = fmaf(v3, v3, sV2[3]);
    Mr[0][ni] = M0; Mr[1][ni] = M1; Mr[2][ni] = M2; Mr[3][ni] = M3;
    Vr[0][ni] = v0; Vr[1][ni] = v1; Vr[2][ni] = v2; Vr[3][ni] = v3;
  }
  for (int i = t; i < NN; i += 256) {
    float c = (float)cb[i];
    float u0 = Ur[i], u1 = Ur[2052 + i], u2 = Ur[4104 + i], u3 = Ur[6156 + i];
    sU2[0] = fmaf(c * u0, u0, sU2[0]);
    sU2[1] = fmaf(c * u1, u1, sU2[1]);
    sU2[2] = fmaf(c * u2, u2, sU2[2]);
    sU2[3] = fmaf(c * u3, u3, sU2[3]);
  }
  float st[20];
#pragma unroll
  for (int r = 0; r < 4; r++) {
    st[r] = sG[r]; st[4 + r] = sVG[r]; st[8 + r] = sV[r];
    st[12 + r] = sV2[r]; st[16 + r] = sU2[r];
  }
#pragma unroll
  for (int k = 0; k < 20; k++) {
    float a = st[k];
#pragma unroll
    for (int d = 1; d < 64; d <<= 1) a += shflx_f(a, d);
    if (lane == 0) red[k][wave] = a;
  }
  __syncthreads();
  if (t < 4) {
    float g  = red[t][0] + red[t][1] + red[t][2] + red[t][3];
    float vg = red[4 + t][0] + red[4 + t][1] + red[4 + t][2] + red[4 + t][3];
    float v  = red[8 + t][0] + red[8 + t][1] + red[8 + t][2] + red[8 + t][3];
    float v2 = red[12 + t][0] + red[12 + t][1] + red[12 + t][2] + red[12 + t][3];
    float u2 = red[16 + t][0] + red[16 + t][1] + red[16 + t][2] + red[16 + t][3];
    float sumY  = g + (float)KK * v;
    float sumY2 = u2 + 2.f * vg + (float)KK * v2;
    const float inv = 1.f / (float)(NN * KK);
    float mu = sumY * inv;
    float var = fmaxf(sumY2 * inv - mu * mu, 0.f);
    smv[t] = mu;
    smv[4 + t] = rsqrtf(var + EPSF);
  }
  __syncthreads();
  const float mu0 = smv[0], mu1 = smv[1], mu2 = smv[2], mu3 = smv[3];
  const float i0 = smv[4], i1 = smv[5], i2 = smv[6], i3 = smv[7];
  const int kc = (gbase + o0) >> 5, c32 = (gbase + o0) & 31;
#pragma unroll
  for (int ni = 0; ni < 8; ni++) {
    const int n = t + ni * 256;
    float z0 = (Mr[0][ni] + Vr[0][ni] - mu0) * i0; z0 = z0 >= 0.f ? z0 : 0.2f * z0;
    float z1 = (Mr[1][ni] + Vr[1][ni] - mu1) * i1; z1 = z1 >= 0.f ? z1 : 0.2f * z1;
    float z2 = (Mr[2][ni] + Vr[2][ni] - mu2) * i2; z2 = z2 >= 0.f ? z2 : 0.2f * z2;
    float z3 = (Mr[3][ni] + Vr[3][ni] - mu3) * i3; z3 = z3 >= 0.f ? z3 : 0.2f * z3;
    v4h h4, l4;
    h4[0] = (_Float16)z0; l4[0] = (_Float16)(z0 - (float)h4[0]);
    h4[1] = (_Float16)z1; l4[1] = (_Float16)(z1 - (float)h4[1]);
    h4[2] = (_Float16)z2; l4[2] = (_Float16)(z2 - (float)h4[2]);
    h4[3] = (_Float16)z3; l4[3] = (_Float16)(z3 - (float)h4[3]);
    size_t yoff = (((size_t)b * 16 + kc) * NN + n) * 32 + c32;
    *(v4h*)(y5h + yoff) = h4;
    *(v4h*)(y5l + yoff) = l4;
    if (nxh) {
      size_t noff = ((size_t)b * NN + n) * CpN + o0;
      *(v4h*)(nxh + noff) = h4;
      *(v4h*)(nxl + noff) = l4;
      atomicAdd(&xx[b * NN + n], z0 * z0 + z1 * z1 + z2 * z2 + z3 * z3);
    }
  }
}

// ---------------- y5 = w5 * xcat via MFMA (f16 hi/lo 3-product) ----------------
__global__ __launch_bounds__(256) void y5_mfma(const _Float16* __restrict__ w5h,
    const _Float16* __restrict__ w5l, const _Float16* __restrict__ xh,
    const _Float16* __restrict__ xl, float* __restrict__ y5)
{
  const int lane = threadIdx.x & 63, wave = threadIdx.x >> 6;
  const int col = lane & 15, quad = lane >> 4, quad8 = quad * 8;
  const int b = blockIdx.z;
  const int o0 = blockIdx.x * 256 + wave * 64;
  const int nb0 = blockIdx.y * 128;
  v4f acc[4][8];
#pragma unroll
  for (int a = 0; a < 4; a++)
#pragma unroll
    for (int t = 0; t < 8; t++) acc[a][t] = {0.f, 0.f, 0.f, 0.f};

  for (int kc = 0; kc < 16; kc++) {
    v8h Ah[4], Al[4];
#pragma unroll
    for (int a = 0; a < 4; a++) {
      size_t off = (size_t)(o0 + a * 16 + col) * 512 + kc * 32 + quad8;
      Ah[a] = *(const v8h*)(w5h + off);
      Al[a] = *(const v8h*)(w5l + off);
    }
#pragma unroll
    for (int t = 0; t < 8; t++) {
      int n = nb0 + t * 16 + col;
      size_t boff = (((size_t)b * 16 + kc) * NN + n) * 32 + quad8;
      v8h Bh = *(const v8h*)(xh + boff);
      v8h Bl = *(const v8h*)(xl + boff);
#pragma unroll
      for (int a = 0; a < 4; a++) {
        acc[a][t] = __builtin_amdgcn_mfma_f32_16x16x32_f16(Ah[a], Bh, acc[a][t], 0, 0, 0);
        acc[a][t] = __builtin_amdgcn_mfma_f32_16x16x32_f16(Ah[a], Bl, acc[a][t], 0, 0, 0);
        acc[a][t] = __builtin_amdgcn_mfma_f32_16x16x32_f16(Al[a], Bh, acc[a][t], 0, 0, 0);
      }
    }
  }
#pragma unroll
  for (int a = 0; a < 4; a++)
#pragma unroll
    for (int t = 0; t < 8; t++)
#pragma unroll
      for (int j = 0; j < 4; j++)
        y5[((size_t)b * 512 + o0 + a * 16 + quad * 4 + j) * NN + nb0 + t * 16 + col] = acc[a][t][j];
}

__global__ __launch_bounds__(256) void bn5stat_kernel(const float* __restrict__ y5,
    float* __restrict__ bn5) {
  __shared__ float rs[4], rq[4];
  const int o = blockIdx.x, t = threadIdx.x, lane = t & 63, wave = t >> 6;
  float s = 0.f, q = 0.f;
  for (int b = 0; b < NB; b++) {
    const float* p = y5 + ((size_t)b * 512 + o) * NN;
    for (int n = t; n < NN; n += 256) { float v = p[n]; s += v; q = fmaf(v, v, q); }
  }
#pragma unroll
  for (int d = 1; d < 64; d <<= 1) { s += shflx_f(s, d); q += shflx_f(q, d); }
  if (lane == 0) { rs[wave] = s; rq[wave] = q; }
  __syncthreads();
  if (t == 0) {
    float S = rs[0] + rs[1] + rs[2] + rs[3];
    float Q = rq[0] + rq[1] + rq[2] + rq[3];
    const float inv = 1.f / (float)(NB * NN);
    float mu = S * inv;
    float var = fmaxf(Q * inv - mu * mu, 0.f);
    bn5[o] = mu;
    bn5[512 + o] = rsqrtf(var + EPSF);
  }
}

__global__ __launch_bounds__(256) void final_kernel(const float* __restrict__ y5,
    const float* __restrict__ bn5, const float* __restrict__ gamma,
    const float* __restrict__ beta, float* __restrict__ out)
{
  __shared__ float rm[4], rs[4];
  const int o = blockIdx.x, b = blockIdx.y, t = threadIdx.x, lane = t & 63, wave = t >> 6;
  const float mu = bn5[o], iv = bn5[512 + o], g = gamma[o], be = beta[o];
  const float* p = y5 + ((size_t)b * 512 + o) * NN;
  float mx = -3.4e38f, sm = 0.f;
  for (int n = t; n < NN; n += 256) {
    float z = (p[n] - mu) * iv;
    z = z * g + be;
    z = (z >= 0.f) ? z : 0.2f * z;
    mx = fmaxf(mx, z);
    sm += z;
  }
#pragma unroll
  for (int d = 1; d < 64; d <<= 1) { mx = fmaxf(mx, shflx_f(mx, d)); sm += shflx_f(sm, d); }
  if (lane == 0) { rm[wave] = mx; rs[wave] = sm; }
  __syncthreads();
  if (t == 0) {
    float M = fmaxf(fmaxf(rm[0], rm[1]), fmaxf(rm[2], rm[3]));
    float S = rs[0] + rs[1] + rs[2] + rs[3];
    out[(size_t)b * 1024 + o] = M;
    out[(size_t)b * 1024 + 512 + o] = S * (1.f / NN);
  }
}

extern "C" void kernel_launch(void* const* d_in, const int* in_sizes, int n_in,
                              void* d_out, int out_size, void* d_ws, size_t ws_size,
                              hipStream_t stream)
{
  (void)in_sizes; (void)n_in; (void)out_size; (void)ws_size;
  const float* x  = (const float*)d_in[0];
  const float* w1 = (const float*)d_in[1];
  const float* w2 = (const float*)d_in[2];
  const float* w3 = (const float*)d_in[3];
  const float* w4 = (const float*)d_in[4];
  const float* w5 = (const float*)d_in[5];
  const float* g5 = (const float*)d_in[6];
  const float* b5 = (const float*)d_in[7];
  float* out = (float*)d_out;

  // ---- workspace (same 137 MB footprint as the passing round-6 layout) ----
  float* ws   = (float*)d_ws;
  // [0, 16777216) floats: y5 fragment buffers (hi 33.5MB | lo 33.5MB)
  _Float16* y5fh = (_Float16*)ws;
  _Float16* y5fl = y5fh + 16777216;
  float* Ub   = ws + 16777216;              // 8.39M floats (33.5MB)
  float* Vb   = Ub + 8388608;               // 8.39M floats (33.5MB)
  int*   idxb = (int*)(Vb + 8388608);       // 16*2048*20 ints
  float* xxb  = (float*)(idxb + 655360);    // 32768 floats
  float* bn5  = xxb + 32768;                // 1024

  // Vb carve-up: xth | xtl | cntb(survivors) | cnth(histogram) | weight stash
  _Float16* xth = (_Float16*)Vb;                       // 4.19M halves
  _Float16* xtl = xth + 4194304;                       // 4.19M halves
  int* cntb = (int*)(Vb + 4194304);                    // 65536 ints
  int* cnth = (int*)(Vb + 4259840);                    // 32768 ints
  _Float16* wuh = (_Float16*)(Vb + 4292608);           // 4 x 32768 halves
  _Float16* wul = wuh + 32768;
  _Float16* wvh = wul + 32768;
  _Float16* wvl = wvh + 32768;

  ull* slist = (ull*)Ub;       // survivor lists (dead after merge)
  float* Uo = Ub;              // U chunk [b][Och][NN], <= 4.19M floats
  float* Vo = Ub + 4194304;    // V chunk
  float* y5 = Ub;              // y5 fp32 spans Ub+Vb after layer 4

  _Float16* w5h = (_Float16*)idxb;  // idx dead after last edge2
  _Float16* w5l = w5h + 262144;

  struct Lyr { int C, KB, O, coff, CpN; const float* w; };
  const Lyr L[4] = {
    { 3,   1, 64,  0,   64,  w1 },
    { 64,  2, 64,  64,  64,  w2 },
    { 64,  2, 128, 128, 128, w3 },
    { 128, 4, 256, 256, 0,   w4 },
  };

  prep_kernel<<<dim3(NN / 256, NB), 256, 0, stream>>>(x, xth, xtl, xxb, 3, 1, 3L * NN);

  for (int l = 0; l < 4; l++) {
    const int Cp = L[l].KB * 32, O = L[l].O, C = L[l].C;
    switch (L[l].KB) {
      case 1: knn2<1><<<dim3(NB * 2, NN / 256), 256, 0, stream>>>(xth, xtl, xxb, slist, cntb); break;
      case 2: knn2<2><<<dim3(NB * 2, NN / 256), 256, 0, stream>>>(xth, xtl, xxb, slist, cntb); break;
      default: knn2<4><<<dim3(NB * 2, NN / 256), 256, 0, stream>>>(xth, xtl, xxb, slist, cntb); break;
    }
    knn_merge<<<dim3(NN / 4, NB), 256, 0, stream>>>(slist, cntb, xth, xtl, xxb, idxb, Cp, C);
    const int wblocks = (O * Cp + 255) / 256;
    setup_kernel<<<NB + wblocks, 256, 0, stream>>>(idxb, cnth, L[l].w,
        wuh, wul, wvh, wvl, C, Cp, O, xxb, l < 3 ? 1 : 0);
    const int nchunks = (O > 128) ? 2 : 1;
    const int Och = O / nchunks;
    for (int c = 0; c < nchunks; c++) {
      const int c0 = c * Och;
      uv_mfma<<<dim3(Och / 32, NN / 512, NB), 256, 0, stream>>>(
          wuh + (size_t)c0 * Cp, wul + (size_t)c0 * Cp,
          wvh + (size_t)c0 * Cp, wvl + (size_t)c0 * Cp,
          xth, xtl, Uo, Vo, Cp, Och);
      edge2<<<dim3(Och / 4, NB), 256, 0, stream>>>(Uo, Vo, idxb, cnth,
          (l < 3) ? xth : (_Float16*)nullptr, (l < 3) ? xtl : (_Float16*)nullptr,
          L[l].CpN, y5fh, y5fl, L[l].coff + c0, xxb, Och);
    }
  }
  w5cvt<<<1024, 256, 0, stream>>>(w5, w5h, w5l);
  y5_mfma<<<dim3(2, NN / 128, NB), 256, 0, stream>>>(w5h, w5l, y5fh, y5fl, y5);
  bn5stat_kernel<<<512, 256, 0, stream>>>(y5, bn5);
  final_kernel<<<dim3(512, NB), 256, 0, stream>>>(y5, bn5, g5, b5, out);
}

// Round 8
// 2561.645 us; speedup vs baseline: 1.0018x; 1.0018x over previous
//
#include <hip/hip_runtime.h>

#define NN 2048      // points
#define NB 16        // batch
#define KK 20        // k neighbors
#define EPSF 1e-5f

typedef unsigned long long ull;
typedef _Float16 v8h __attribute__((ext_vector_type(8)));
typedef float v4f __attribute__((ext_vector_type(4)));

__device__ __forceinline__ float shflx_f(float v, int m) { return __shfl_xor(v, m, 64); }
__device__ __forceinline__ ull shflx_u64(ull v, int m) {
  int lo = __shfl_xor((int)(unsigned)v, m, 64);
  int hi = __shfl_xor((int)(unsigned)(v >> 32), m, 64);
  return (((ull)(unsigned)hi) << 32) | (unsigned)lo;
}
__device__ __forceinline__ ull packkey(float s, int n) {
  unsigned u = __float_as_uint(s);
  u = (u & 0x80000000u) ? ~u : (u | 0x80000000u);
  return (((ull)u) << 32) | (unsigned)(2047 - n);   // ties -> lowest index wins under max
}

// ---------------- prep: x[C][N] fp32 -> fragment-ready f16 hi/lo [n][Cp] + xx ----
__global__ __launch_bounds__(256) void prep_kernel(const float* __restrict__ x,
    _Float16* __restrict__ xh, _Float16* __restrict__ xl, float* __restrict__ xx,
    int C, int KB, long bstride)
{
  const int b = blockIdx.y;
  const int n = blockIdx.x * 256 + threadIdx.x;
  const float* xb = x + (size_t)b * bstride;
  const int Cp = KB * 32;
  _Float16* ph = xh + ((size_t)b * NN + n) * Cp;
  _Float16* pl = xl + ((size_t)b * NN + n) * Cp;
  float s = 0.f;
  for (int kb = 0; kb < KB; kb++) {
    for (int g = 0; g < 4; g++) {
      v8h hv, lv;
#pragma unroll
      for (int j = 0; j < 8; j++) {
        int c = kb * 32 + g * 8 + j;
        float v = (c < C) ? xb[(size_t)c * NN + n] : 0.f;
        _Float16 h = (_Float16)v;
        hv[j] = h;
        lv[j] = (_Float16)(v - (float)h);
        s = fmaf(v, v, s);
      }
      *(v8h*)(ph + kb * 32 + g * 8) = hv;
      *(v8h*)(pl + kb * 32 + g * 8) = lv;
    }
  }
  xx[b * NN + n] = s;
}

// ---------------- tile scorer: 64 queries (4 A-tiles) x 16 candidates ----------
template<int KB>
__device__ __forceinline__ void tile_scores(const v8h (&Bh)[KB], const v8h (&Bl)[KB],
    const v8h (&Ah)[4][KB], const v8h (&Al)[4][KB], float xv, v4f (&out)[4])
{
#pragma unroll
  for (int a = 0; a < 4; a++) {
    v4f a0 = {0.f, 0.f, 0.f, 0.f};
    v4f a1 = {0.f, 0.f, 0.f, 0.f};
#pragma unroll
    for (int kb = 0; kb < KB; kb++) {
      v4f& acc = (kb & 1) ? a1 : a0;
      acc = __builtin_amdgcn_mfma_f32_16x16x32_f16(Ah[a][kb], Bh[kb], acc, 0, 0, 0);
      acc = __builtin_amdgcn_mfma_f32_16x16x32_f16(Ah[a][kb], Bl[kb], acc, 0, 0, 0);
      acc = __builtin_amdgcn_mfma_f32_16x16x32_f16(Al[a][kb], Bh[kb], acc, 0, 0, 0);
    }
    v4f s = a0 + a1;
#pragma unroll
    for (int j = 0; j < 4; j++) out[a][j] = s[j] - 0.5f * xv;
  }
}

// ---------------- kNN stage 1: 4-deep B prefetch ring, two passes -------------
template<int KB>
__global__ __launch_bounds__(256, 1) void knn2(
    const _Float16* __restrict__ xh, const _Float16* __restrict__ xl,
    const float* __restrict__ xxg, ull* __restrict__ slistG, int* __restrict__ cntG)
{
  __shared__ float gmL[256][33];
  __shared__ float tauL[256];
  __shared__ int scnt[256];

  const int t = threadIdx.x;
  const int lane = t & 63;
  const int wave = t >> 6;
  const int col = lane & 15;
  const int quad = lane >> 4;
  const int quad8 = quad * 8;
  const int b = blockIdx.x >> 1;
  const int chunk = blockIdx.x & 1;
  const int qg = blockIdx.y;
  const int Cp = KB * 32;
  const int cb = chunk * 1024;
  const _Float16* xhb = xh + (size_t)b * NN * Cp;
  const _Float16* xlb = xl + (size_t)b * NN * Cp;
  const float* xxb = xxg + b * NN;

  v8h Ah[4][KB], Al[4][KB];
  const int qw = qg * 256 + wave * 64;
#pragma unroll
  for (int a = 0; a < 4; a++) {
    const _Float16* pa = xhb + (size_t)(qw + a * 16 + col) * Cp + quad8;
    const _Float16* pb = xlb + (size_t)(qw + a * 16 + col) * Cp + quad8;
#pragma unroll
    for (int kb = 0; kb < KB; kb++) {
      Ah[a][kb] = *(const v8h*)(pa + kb * 32);
      Al[a][kb] = *(const v8h*)(pb + kb * 32);
    }
  }

  v8h Bh[4][KB], Bl[4][KB];
  float xvb[4];
  auto loadB = [&](int slot, int tt) {
    int t2 = tt < 63 ? tt : 63;
    int n = cb + t2 * 16 + col;
    const _Float16* pb = xhb + (size_t)n * Cp + quad8;
    const _Float16* pl = xlb + (size_t)n * Cp + quad8;
#pragma unroll
    for (int kb = 0; kb < KB; kb++) {
      Bh[slot][kb] = *(const v8h*)(pb + kb * 32);
      Bl[slot][kb] = *(const v8h*)(pl + kb * 32);
    }
    xvb[slot] = xxb[n];
  };

  // ---- pass 1: group maxima (16 cols x 2 tile-parities = 32 groups/query) ----
  float gm[4][8];
#pragma unroll
  for (int a = 0; a < 4; a++)
#pragma unroll
    for (int j = 0; j < 8; j++) gm[a][j] = -3.4e38f;

#pragma unroll
  for (int s = 0; s < 4; s++) loadB(s, s);
  for (int tt = 0; tt < 64; tt += 4) {
#pragma unroll
    for (int s = 0; s < 4; s++) {
      v4f out[4];
      tile_scores<KB>(Bh[s], Bl[s], Ah, Al, xvb[s], out);
      loadB(s, tt + 4 + s);
      const int par = s & 1;
#pragma unroll
      for (int a = 0; a < 4; a++)
#pragma unroll
        for (int j = 0; j < 4; j++) gm[a][j * 2 + par] = fmaxf(gm[a][j * 2 + par], out[a][j]);
    }
  }

#pragma unroll
  for (int a = 0; a < 4; a++)
#pragma unroll
    for (int j = 0; j < 4; j++) {
      int qi = wave * 64 + a * 16 + quad * 4 + j;
      gmL[qi][col * 2 + 0] = gm[a][j * 2 + 0];
      gmL[qi][col * 2 + 1] = gm[a][j * 2 + 1];
    }
  scnt[t] = 0;
  asm volatile("s_waitcnt lgkmcnt(0)" ::: "memory");

  // tau = rank-19 of 32 group maxima (provably <= true 20th score)
  for (int r = 0; r < 32; r++) {
    const int q = wave * 64 + r * 2 + (lane >> 5);
    const int idx = lane & 31;
    float v = gmL[q][idx];
#pragma unroll
    for (int kk = 2; kk <= 32; kk <<= 1) {
#pragma unroll
      for (int m = kk >> 1; m >= 1; m >>= 1) {
        float o = shflx_f(v, m);
        bool keepmax = ((idx & kk) == 0) == ((idx & m) == 0);
        v = keepmax ? fmaxf(v, o) : fminf(v, o);
      }
    }
    if (idx == 19) tauL[q] = v;
  }
  asm volatile("s_waitcnt lgkmcnt(0)" ::: "memory");

  float tq[4][4];
#pragma unroll
  for (int a = 0; a < 4; a++)
#pragma unroll
    for (int j = 0; j < 4; j++) tq[a][j] = tauL[wave * 64 + a * 16 + quad * 4 + j];

  // ---- pass 2: bitwise-identical rescore, compact survivors >= tau ----
  ull* slB = slistG + (((size_t)b * NN + qg * 256) * 2 + chunk) * 64;
#pragma unroll
  for (int s = 0; s < 4; s++) loadB(s, s);
  for (int tt = 0; tt < 64; tt += 4) {
#pragma unroll
    for (int s = 0; s < 4; s++) {
      v4f out[4];
      tile_scores<KB>(Bh[s], Bl[s], Ah, Al, xvb[s], out);
      loadB(s, tt + 4 + s);
      int n = cb + (tt + s) * 16 + col;
#pragma unroll
      for (int a = 0; a < 4; a++)
#pragma unroll
        for (int j = 0; j < 4; j++) {
          float sc = out[a][j];
          if (sc >= tq[a][j]) {
            int qi = wave * 64 + a * 16 + quad * 4 + j;
            int pos = atomicAdd(&scnt[qi], 1);
            if (pos < 64) slB[(size_t)qi * 128 + pos] = packkey(sc, n);
          }
        }
    }
  }
  asm volatile("s_waitcnt lgkmcnt(0)" ::: "memory");
  cntG[((size_t)b * NN + qg * 256 + t) * 2 + chunk] = scnt[t];
}

// ---------------- kNN stage 2: merge 2 chunk survivor lists -> top-20 --------
__global__ __launch_bounds__(256) void knn_merge(const ull* __restrict__ slistG,
    const int* __restrict__ cntG, const _Float16* __restrict__ xh,
    const _Float16* __restrict__ xl, const float* __restrict__ xxg,
    int* __restrict__ idxout, int Cp, int C)
{
  const int lane = threadIdx.x & 63, wave = threadIdx.x >> 6;
  const int b = blockIdx.y;
  const int q = blockIdx.x * 4 + wave;
  const int c0 = cntG[((size_t)b * NN + q) * 2 + 0];
  const int c1 = cntG[((size_t)b * NN + q) * 2 + 1];
  int* op = idxout + ((size_t)b * NN + q) * KK;

  if (c0 <= 64 && c1 <= 64) {
    const ull* s0 = slistG + ((size_t)b * NN + q) * 128;
    const int total = c0 + c1;
    ull e0 = 0, e1 = 0;
    int p0 = lane, p1 = lane + 64;
    if (p0 < total) e0 = (p0 < c0) ? s0[p0] : s0[64 + p0 - c0];
    if (p1 < total) e1 = (p1 < c0) ? s0[p1] : s0[64 + p1 - c0];
    for (int s = 0; s < KK; s++) {
      ull m = e0 > e1 ? e0 : e1;
      ull g = m;
#pragma unroll
      for (int d = 1; d < 64; d <<= 1) { ull o = shflx_u64(g, d); g = o > g ? o : g; }
      if (lane == 0) op[s] = 2047 - (int)(g & 0xFFFFFFFFu);
      if (e0 == g) e0 = 0; else if (e1 == g) e1 = 0;
    }
  } else {
    // exact fallback (survivor cap overflow — expected never): full fp32 rescan
    const _Float16* qh = xh + ((size_t)b * NN + q) * Cp;
    const _Float16* ql = xl + ((size_t)b * NN + q) * Cp;
    const float* xxb = xxg + b * NN;
    float sc[32];
#pragma unroll
    for (int i = 0; i < 32; i++) sc[i] = -0.5f * xxb[lane + 64 * i];
    for (int c = 0; c < C; c++) {
      float qv = (float)qh[c] + (float)ql[c];
      for (int i = 0; i < 32; i++) {
        int n = lane + 64 * i;
        float bv = (float)xh[((size_t)b * NN + n) * Cp + c] + (float)xl[((size_t)b * NN + n) * Cp + c];
        sc[i] = fmaf(qv, bv, sc[i]);
      }
    }
    for (int s = 0; s < KK; s++) {
      ull m = 0; int mi = -1;
      for (int i = 0; i < 32; i++) {
        ull k = packkey(sc[i], lane + 64 * i);
        if (k > m) { m = k; mi = i; }
      }
      ull g = m;
#pragma unroll
      for (int d = 1; d < 64; d <<= 1) { ull o = shflx_u64(g, d); g = o > g ? o : g; }
      if (lane == 0) op[s] = 2047 - (int)(g & 0xFFFFFFFFu);
      if (m == g && mi >= 0) sc[mi] = -3.4e38f;
    }
  }
}

// ---------------- per-layer setup: idx histogram + weight convert ----------------
__global__ __launch_bounds__(256) void setup_kernel(const int* __restrict__ idx,
    int* __restrict__ cnt, const float* __restrict__ w,
    _Float16* __restrict__ wuh, _Float16* __restrict__ wul,
    _Float16* __restrict__ wvh, _Float16* __restrict__ wvl,
    int C, int Cp, int O)
{
  __shared__ int h[2048];
  const int blk = blockIdx.x, t = threadIdx.x;
  if (blk < NB) {
    const int b = blk;
    for (int i = t; i < 2048; i += 256) h[i] = 0;
    __syncthreads();
    const int* ib = idx + (size_t)b * NN * KK;
    for (int i = t; i < NN * KK; i += 256) atomicAdd(&h[ib[i]], 1);
    __syncthreads();
    for (int i = t; i < 2048; i += 256) cnt[b * 2048 + i] = h[i];
  } else {
    int e = (blk - NB) * 256 + t;
    if (e < O * Cp) {
      int o = e / Cp, c = e - o * Cp;
      float a = 0.f, bv = 0.f;
      if (c < C) { a = w[o * 2 * C + c]; bv = w[o * 2 * C + C + c]; }
      float v = bv - a;
      _Float16 ah = (_Float16)a; wuh[e] = ah; wul[e] = (_Float16)(a - (float)ah);
      _Float16 vh = (_Float16)v; wvh[e] = vh; wvl[e] = (_Float16)(v - (float)vh);
    }
  }
}

__global__ __launch_bounds__(256) void w5cvt(const float* __restrict__ w5,
    _Float16* __restrict__ w5h, _Float16* __restrict__ w5l)
{
  int idx = blockIdx.x * 256 + threadIdx.x;
  float v = w5[idx];
  _Float16 h = (_Float16)v;
  w5h[idx] = h;
  w5l[idx] = (_Float16)(v - (float)h);
}

// ---------------- U/V chunk (64 out-ch) via MFMA -----------------------------
__global__ __launch_bounds__(256) void uv_mfma(const _Float16* __restrict__ wuh,
    const _Float16* __restrict__ wul, const _Float16* __restrict__ wvh,
    const _Float16* __restrict__ wvl, const _Float16* __restrict__ xh,
    const _Float16* __restrict__ xl, float* __restrict__ Uc, float* __restrict__ Vc,
    int Cp)
{
  const int lane = threadIdx.x & 63, wave = threadIdx.x >> 6;
  const int col = lane & 15, quad = lane >> 4, quad8 = quad * 8;
  const int b = blockIdx.z;
  const int o0 = blockIdx.x * 32;
  const int nb0 = blockIdx.y * 512 + wave * 128;
  v4f aU[2][8], aV[2][8];
#pragma unroll
  for (int a = 0; a < 2; a++)
#pragma unroll
    for (int t = 0; t < 8; t++) { aU[a][t] = {0.f,0.f,0.f,0.f}; aV[a][t] = {0.f,0.f,0.f,0.f}; }

  const int KBr = Cp >> 5;
  for (int kb = 0; kb < KBr; kb++) {
    v8h Uh[2], Ul[2], Vh[2], Vl[2];
#pragma unroll
    for (int a = 0; a < 2; a++) {
      size_t off = (size_t)(o0 + a * 16 + col) * Cp + kb * 32 + quad8;
      Uh[a] = *(const v8h*)(wuh + off);
      Ul[a] = *(const v8h*)(wul + off);
      Vh[a] = *(const v8h*)(wvh + off);
      Vl[a] = *(const v8h*)(wvl + off);
    }
#pragma unroll
    for (int t = 0; t < 8; t++) {
      int n = nb0 + t * 16 + col;
      size_t boff = ((size_t)b * NN + n) * Cp + kb * 32 + quad8;
      v8h Bh = *(const v8h*)(xh + boff);
      v8h Bl = *(const v8h*)(xl + boff);
#pragma unroll
      for (int a = 0; a < 2; a++) {
        aU[a][t] = __builtin_amdgcn_mfma_f32_16x16x32_f16(Uh[a], Bh, aU[a][t], 0, 0, 0);
        aU[a][t] = __builtin_amdgcn_mfma_f32_16x16x32_f16(Uh[a], Bl, aU[a][t], 0, 0, 0);
        aU[a][t] = __builtin_amdgcn_mfma_f32_16x16x32_f16(Ul[a], Bh, aU[a][t], 0, 0, 0);
        aV[a][t] = __builtin_amdgcn_mfma_f32_16x16x32_f16(Vh[a], Bh, aV[a][t], 0, 0, 0);
        aV[a][t] = __builtin_amdgcn_mfma_f32_16x16x32_f16(Vh[a], Bl, aV[a][t], 0, 0, 0);
        aV[a][t] = __builtin_amdgcn_mfma_f32_16x16x32_f16(Vl[a], Bh, aV[a][t], 0, 0, 0);
      }
    }
  }
#pragma unroll
  for (int a = 0; a < 2; a++)
#pragma unroll
    for (int t = 0; t < 8; t++)
#pragma unroll
      for (int j = 0; j < 4; j++) {
        size_t base = ((size_t)b * 64 + o0 + a * 16 + quad * 4 + j) * NN + nb0 + t * 16 + col;
        Uc[base] = aU[a][t][j];
        Vc[base] = aV[a][t][j];
      }
}

// ---------------- edge3: ONE gather pass + closed-form stats, fp32 coalesced out
// sumY = sG + K*sV ; sumY2 = sum_m cnt[m]*U[m]^2 + 2*sVG + K*sV2
// max_j y = V[n] + max_j U[idx[n,j]]; leaky-relu commutes with the positive scale.
__global__ __launch_bounds__(256) void edge3(const float* __restrict__ U,
    const float* __restrict__ V, const int* __restrict__ idx,
    const int* __restrict__ cnt, float* __restrict__ xo)
{
  __shared__ float Ur[4 * 2052];
  __shared__ float red[20][4];
  __shared__ float smv[8];
  const int b = blockIdx.y, o0 = blockIdx.x * 4;
  const int t = threadIdx.x, lane = t & 63, wave = t >> 6;
  for (int r = 0; r < 4; r++)
    for (int i = t; i < NN; i += 256)
      Ur[r * 2052 + i] = U[((size_t)b * 64 + o0 + r) * NN + i];
  __syncthreads();
  const float* Vp = V + ((size_t)b * 64 + o0) * NN;
  const int* ib = idx + (size_t)b * NN * KK;
  const int* cb = cnt + b * NN;

  float sG[4] = {0,0,0,0}, sVG[4] = {0,0,0,0}, sV[4] = {0,0,0,0},
        sV2[4] = {0,0,0,0}, sU2[4] = {0,0,0,0};
  float Mr[4][8], Vr[4][8];
#pragma unroll
  for (int ni = 0; ni < 8; ni++) {
    const int n = t + ni * 256;
    const int* ip = ib + (size_t)n * KK;
    float G0 = 0, G1 = 0, G2 = 0, G3 = 0;
    float M0 = -3.4e38f, M1 = M0, M2 = M0, M3 = M0;
#pragma unroll
    for (int j = 0; j < KK; j++) {
      int m = ip[j];
      float u0 = Ur[m], u1 = Ur[2052 + m], u2 = Ur[4104 + m], u3 = Ur[6156 + m];
      G0 += u0; M0 = fmaxf(M0, u0);
      G1 += u1; M1 = fmaxf(M1, u1);
      G2 += u2; M2 = fmaxf(M2, u2);
      G3 += u3; M3 = fmaxf(M3, u3);
    }
    float v0 = Vp[n], v1 = Vp[NN + n], v2 = Vp[2 * NN + n], v3 = Vp[3 * NN + n];
    sG[0] += G0; sVG[0] = fmaf(v0, G0, sVG[0]); sV[0] += v0; sV2[0] = fmaf(v0, v0, sV2[0]);
    sG[1] += G1; sVG[1] = fmaf(v1, G1, sVG[1]); sV[1] += v1; sV2[1] = fmaf(v1, v1, sV2[1]);
    sG[2] += G2; sVG[2] = fmaf(v2, G2, sVG[2]); sV[2] += v2; sV2[2] = fmaf(v2, v2, sV2[2]);
    sG[3] += G3; sVG[3] = fmaf(v3, G3, sVG[3]); sV[3] += v3; sV2[3] = fmaf(v3, v3, sV2[3]);
    Mr[0][ni] = M0; Mr[1][ni] = M1; Mr[2][ni] = M2; Mr[3][ni] = M3;
    Vr[0][ni] = v0; Vr[1][ni] = v1; Vr[2][ni] = v2; Vr[3][ni] = v3;
  }
  for (int i = t; i < NN; i += 256) {
    float c = (float)cb[i];
    float u0 = Ur[i], u1 = Ur[2052 + i], u2 = Ur[4104 + i], u3 = Ur[6156 + i];
    sU2[0] = fmaf(c * u0, u0, sU2[0]);
    sU2[1] = fmaf(c * u1, u1, sU2[1]);
    sU2[2] = fmaf(c * u2, u2, sU2[2]);
    sU2[3] = fmaf(c * u3, u3, sU2[3]);
  }
  float st[20];
#pragma unroll
  for (int r = 0; r < 4; r++) {
    st[r] = sG[r]; st[4 + r] = sVG[r]; st[8 + r] = sV[r];
    st[12 + r] = sV2[r]; st[16 + r] = sU2[r];
  }
#pragma unroll
  for (int k = 0; k < 20; k++) {
    float a = st[k];
#pragma unroll
    for (int d = 1; d < 64; d <<= 1) a += shflx_f(a, d);
    if (lane == 0) red[k][wave] = a;
  }
  __syncthreads();
  if (t < 4) {
    float g  = red[t][0] + red[t][1] + red[t][2] + red[t][3];
    float vg = red[4 + t][0] + red[4 + t][1] + red[4 + t][2] + red[4 + t][3];
    float v  = red[8 + t][0] + red[8 + t][1] + red[8 + t][2] + red[8 + t][3];
    float v2 = red[12 + t][0] + red[12 + t][1] + red[12 + t][2] + red[12 + t][3];
    float u2 = red[16 + t][0] + red[16 + t][1] + red[16 + t][2] + red[16 + t][3];
    float sumY  = g + (float)KK * v;
    float sumY2 = u2 + 2.f * vg + (float)KK * v2;
    const float inv = 1.f / (float)(NN * KK);
    float mu = sumY * inv;
    float var = fmaxf(sumY2 * inv - mu * mu, 0.f);
    smv[t] = mu;
    smv[4 + t] = rsqrtf(var + EPSF);
  }
  __syncthreads();
  const float mu0 = smv[0], mu1 = smv[1], mu2 = smv[2], mu3 = smv[3];
  const float i0 = smv[4], i1 = smv[5], i2 = smv[6], i3 = smv[7];
#pragma unroll
  for (int ni = 0; ni < 8; ni++) {
    const int n = t + ni * 256;
    float z;
    z = (Mr[0][ni] + Vr[0][ni] - mu0) * i0; xo[((size_t)b * 512 + o0 + 0) * NN + n] = z >= 0.f ? z : 0.2f * z;
    z = (Mr[1][ni] + Vr[1][ni] - mu1) * i1; xo[((size_t)b * 512 + o0 + 1) * NN + n] = z >= 0.f ? z : 0.2f * z;
    z = (Mr[2][ni] + Vr[2][ni] - mu2) * i2; xo[((size_t)b * 512 + o0 + 2) * NN + n] = z >= 0.f ? z : 0.2f * z;
    z = (Mr[3][ni] + Vr[3][ni] - mu3) * i3; xo[((size_t)b * 512 + o0 + 3) * NN + n] = z >= 0.f ? z : 0.2f * z;
  }
}

// ---------------- xcat fp32 [b][c][n] -> f16 hi/lo fragments [b][kc][n][32] ----
__global__ __launch_bounds__(256) void y5cvt_kernel(const float* __restrict__ xcat,
    _Float16* __restrict__ xh, _Float16* __restrict__ xl)
{
  const int b = blockIdx.y;
  const int n = blockIdx.x * 256 + threadIdx.x;
  for (int kc = blockIdx.z * 4; kc < blockIdx.z * 4 + 4; kc++) {
    v8h h[4], l[4];
#pragma unroll
    for (int g = 0; g < 4; g++)
#pragma unroll
      for (int j = 0; j < 8; j++) {
        float v = xcat[((size_t)b * 512 + kc * 32 + g * 8 + j) * NN + n];
        _Float16 hh = (_Float16)v;
        h[g][j] = hh;
        l[g][j] = (_Float16)(v - (float)hh);
      }
    size_t base = (((size_t)b * 16 + kc) * NN + n) * 32;
#pragma unroll
    for (int g = 0; g < 4; g++) {
      *(v8h*)(xh + base + g * 8) = h[g];
      *(v8h*)(xl + base + g * 8) = l[g];
    }
  }
}

// ---------------- y5 = w5 * xcat via MFMA (f16 hi/lo 3-product) ----------------
__global__ __launch_bounds__(256) void y5_mfma(const _Float16* __restrict__ w5h,
    const _Float16* __restrict__ w5l, const _Float16* __restrict__ xh,
    const _Float16* __restrict__ xl, float* __restrict__ y5)
{
  const int lane = threadIdx.x & 63, wave = threadIdx.x >> 6;
  const int col = lane & 15, quad = lane >> 4, quad8 = quad * 8;
  const int b = blockIdx.z;
  const int o0 = blockIdx.x * 256 + wave * 64;
  const int nb0 = blockIdx.y * 128;
  v4f acc[4][8];
#pragma unroll
  for (int a = 0; a < 4; a++)
#pragma unroll
    for (int t = 0; t < 8; t++) acc[a][t] = {0.f, 0.f, 0.f, 0.f};

  for (int kc = 0; kc < 16; kc++) {
    v8h Ah[4], Al[4];
#pragma unroll
    for (int a = 0; a < 4; a++) {
      size_t off = (size_t)(o0 + a * 16 + col) * 512 + kc * 32 + quad8;
      Ah[a] = *(const v8h*)(w5h + off);
      Al[a] = *(const v8h*)(w5l + off);
    }
#pragma unroll
    for (int t = 0; t < 8; t++) {
      int n = nb0 + t * 16 + col;
      size_t boff = (((size_t)b * 16 + kc) * NN + n) * 32 + quad8;
      v8h Bh = *(const v8h*)(xh + boff);
      v8h Bl = *(const v8h*)(xl + boff);
#pragma unroll
      for (int a = 0; a < 4; a++) {
        acc[a][t] = __builtin_amdgcn_mfma_f32_16x16x32_f16(Ah[a], Bh, acc[a][t], 0, 0, 0);
        acc[a][t] = __builtin_amdgcn_mfma_f32_16x16x32_f16(Ah[a], Bl, acc[a][t], 0, 0, 0);
        acc[a][t] = __builtin_amdgcn_mfma_f32_16x16x32_f16(Al[a], Bh, acc[a][t], 0, 0, 0);
      }
    }
  }
#pragma unroll
  for (int a = 0; a < 4; a++)
#pragma unroll
    for (int t = 0; t < 8; t++)
#pragma unroll
      for (int j = 0; j < 4; j++)
        y5[((size_t)b * 512 + o0 + a * 16 + quad * 4 + j) * NN + nb0 + t * 16 + col] = acc[a][t][j];
}

__global__ __launch_bounds__(256) void bn5stat_kernel(const float* __restrict__ y5,
    float* __restrict__ bn5) {
  __shared__ float rs[4], rq[4];
  const int o = blockIdx.x, t = threadIdx.x, lane = t & 63, wave = t >> 6;
  float s = 0.f, q = 0.f;
  for (int b = 0; b < NB; b++) {
    const float* p = y5 + ((size_t)b * 512 + o) * NN;
    for (int n = t; n < NN; n += 256) { float v = p[n]; s += v; q = fmaf(v, v, q); }
  }
#pragma unroll
  for (int d = 1; d < 64; d <<= 1) { s += shflx_f(s, d); q += shflx_f(q, d); }
  if (lane == 0) { rs[wave] = s; rq[wave] = q; }
  __syncthreads();
  if (t == 0) {
    float S = rs[0] + rs[1] + rs[2] + rs[3];
    float Q = rq[0] + rq[1] + rq[2] + rq[3];
    const float inv = 1.f / (float)(NB * NN);
    float mu = S * inv;
    float var = fmaxf(Q * inv - mu * mu, 0.f);
    bn5[o] = mu;
    bn5[512 + o] = rsqrtf(var + EPSF);
  }
}

__global__ __launch_bounds__(256) void final_kernel(const float* __restrict__ y5,
    const float* __restrict__ bn5, const float* __restrict__ gamma,
    const float* __restrict__ beta, float* __restrict__ out)
{
  __shared__ float rm[4], rs[4];
  const int o = blockIdx.x, b = blockIdx.y, t = threadIdx.x, lane = t & 63, wave = t >> 6;
  const float mu = bn5[o], iv = bn5[512 + o], g = gamma[o], be = beta[o];
  const float* p = y5 + ((size_t)b * 512 + o) * NN;
  float mx = -3.4e38f, sm = 0.f;
  for (int n = t; n < NN; n += 256) {
    float z = (p[n] - mu) * iv;
    z = z * g + be;
    z = (z >= 0.f) ? z : 0.2f * z;
    mx = fmaxf(mx, z);
    sm += z;
  }
#pragma unroll
  for (int d = 1; d < 64; d <<= 1) { mx = fmaxf(mx, shflx_f(mx, d)); sm += shflx_f(sm, d); }
  if (lane == 0) { rm[wave] = mx; rs[wave] = sm; }
  __syncthreads();
  if (t == 0) {
    float M = fmaxf(fmaxf(rm[0], rm[1]), fmaxf(rm[2], rm[3]));
    float S = rs[0] + rs[1] + rs[2] + rs[3];
    out[(size_t)b * 1024 + o] = M;
    out[(size_t)b * 1024 + 512 + o] = S * (1.f / NN);
  }
}

extern "C" void kernel_launch(void* const* d_in, const int* in_sizes, int n_in,
                              void* d_out, int out_size, void* d_ws, size_t ws_size,
                              hipStream_t stream)
{
  (void)in_sizes; (void)n_in; (void)out_size; (void)ws_size;
  const float* x  = (const float*)d_in[0];
  const float* w1 = (const float*)d_in[1];
  const float* w2 = (const float*)d_in[2];
  const float* w3 = (const float*)d_in[3];
  const float* w4 = (const float*)d_in[4];
  const float* w5 = (const float*)d_in[5];
  const float* g5 = (const float*)d_in[6];
  const float* b5 = (const float*)d_in[7];
  float* out = (float*)d_out;

  // workspace layout (round-6 proven layout + cnth)
  float* ws   = (float*)d_ws;
  float* xcat = ws;                         // 16*512*2048 fp32 (67.1 MB)
  float* Ub   = xcat + 16777216;            // 8.39M floats (33.5 MB)
  float* Vb   = Ub + 8388608;               // 8.39M floats (33.5 MB)
  int*   idxb = (int*)(Vb + 8388608);       // 16*2048*20 ints
  float* xxb  = (float*)(idxb + 655360);    // 32768 floats
  float* bn5  = xxb + 32768;                // 1024

  // Vb carve-up: xth | xtl | cntb(survivor counts) | Vc(chunk V) | wstash | cnth
  _Float16* xth = (_Float16*)Vb;                       // 4.19M halves
  _Float16* xtl = xth + 4194304;                       // 4.19M halves
  int* cntb = (int*)(Vb + 4194304);                    // 65536 ints
  float* Vc = Vb + 4259840;                            // 2.10M floats (64ch chunk)
  _Float16* wuh = (_Float16*)(Vb + 6356992);           // 4 x 32768 halves
  _Float16* wul = wuh + 32768;
  _Float16* wvh = wul + 32768;
  _Float16* wvl = wvh + 32768;
  int* cnth = (int*)(Vb + 6422528);                    // 32768 ints

  ull* slist = (ull*)Ub;       // survivor lists alias Ub (dead after merge)
  float* Uc = Ub;              // chunk U buffer (64ch) at Ub head

  // y5 stage: w5 frags overwrite idx region (free after edge3); xcf frags reuse
  // Ub+Vb wholesale; y5 fp32 reuses xcat (fully consumed by y5cvt first).
  _Float16* w5h = (_Float16*)idxb;
  _Float16* w5l = w5h + 262144;
  _Float16* xcfh = (_Float16*)Ub;
  _Float16* xcfl = (_Float16*)Vb;
  float* y5 = xcat;

  struct Lyr { const float* xin; long bstride; int C, KB, O, coff; const float* w; };
  const Lyr L[4] = {
    { x,              3L * NN,   3,   1, 64,  0,   w1 },
    { xcat,           512L * NN, 64,  2, 64,  64,  w2 },
    { xcat + 64 * NN, 512L * NN, 64,  2, 128, 128, w3 },
    { xcat + 128 * NN,512L * NN, 128, 4, 256, 256, w4 },
  };

  for (int l = 0; l < 4; l++) {
    const int Cp = L[l].KB * 32, O = L[l].O, C = L[l].C;
    prep_kernel<<<dim3(NN / 256, NB), 256, 0, stream>>>(L[l].xin, xth, xtl, xxb,
                                                        C, L[l].KB, L[l].bstride);
    switch (L[l].KB) {
      case 1: knn2<1><<<dim3(NB * 2, NN / 256), 256, 0, stream>>>(xth, xtl, xxb, slist, cntb); break;
      case 2: knn2<2><<<dim3(NB * 2, NN / 256), 256, 0, stream>>>(xth, xtl, xxb, slist, cntb); break;
      default: knn2<4><<<dim3(NB * 2, NN / 256), 256, 0, stream>>>(xth, xtl, xxb, slist, cntb); break;
    }
    knn_merge<<<dim3(NN / 4, NB), 256, 0, stream>>>(slist, cntb, xth, xtl, xxb, idxb, Cp, C);
    const int wblocks = (O * Cp + 255) / 256;
    setup_kernel<<<NB + wblocks, 256, 0, stream>>>(idxb, cnth, L[l].w,
        wuh, wul, wvh, wvl, C, Cp, O);
    for (int c0 = 0; c0 < O; c0 += 64) {
      uv_mfma<<<dim3(2, NN / 512, NB), 256, 0, stream>>>(
          wuh + (size_t)c0 * Cp, wul + (size_t)c0 * Cp,
          wvh + (size_t)c0 * Cp, wvl + (size_t)c0 * Cp,
          xth, xtl, Uc, Vc, Cp);
      edge3<<<dim3(16, NB), 256, 0, stream>>>(Uc, Vc, idxb, cnth,
          xcat + (size_t)(L[l].coff + c0) * NN);
    }
  }
  w5cvt<<<1024, 256, 0, stream>>>(w5, w5h, w5l);
  y5cvt_kernel<<<dim3(NN / 256, NB, 4), 256, 0, stream>>>(xcat, xcfh, xcfl);
  y5_mfma<<<dim3(2, NN / 128, NB), 256, 0, stream>>>(w5h, w5l, xcfh, xcfl, y5);
  bn5stat_kernel<<<512, 256, 0, stream>>>(y5, bn5);
  final_kernel<<<dim3(512, NB), 256, 0, stream>>>(y5, bn5, g5, b5, out);
}

// Round 10
// 1742.601 us; speedup vs baseline: 1.4727x; 1.4700x over previous
//
#include <hip/hip_runtime.h>

#define NN 2048      // points
#define NB 16        // batch
#define KK 20        // k neighbors
#define EPSF 1e-5f

typedef unsigned long long ull;
typedef _Float16 v8h __attribute__((ext_vector_type(8)));
typedef float v4f __attribute__((ext_vector_type(4)));

__device__ __forceinline__ float shflx_f(float v, int m) { return __shfl_xor(v, m, 64); }
__device__ __forceinline__ ull shflx_u64(ull v, int m) {
  int lo = __shfl_xor((int)(unsigned)v, m, 64);
  int hi = __shfl_xor((int)(unsigned)(v >> 32), m, 64);
  return (((ull)(unsigned)hi) << 32) | (unsigned)lo;
}
__device__ __forceinline__ ull packkey(float s, int n) {
  unsigned u = __float_as_uint(s);
  u = (u & 0x80000000u) ? ~u : (u | 0x80000000u);
  return (((ull)u) << 32) | (unsigned)(2047 - n);   // ties -> lowest index wins under max
}

// ---------------- prep: x[C][N] fp32 -> fragment-ready f16 hi/lo [n][Cp] + xx ----
__global__ __launch_bounds__(256) void prep_kernel(const float* __restrict__ x,
    _Float16* __restrict__ xh, _Float16* __restrict__ xl, float* __restrict__ xx,
    int C, int KB, long bstride)
{
  const int b = blockIdx.y;
  const int n = blockIdx.x * 256 + threadIdx.x;
  const float* xb = x + (size_t)b * bstride;
  const int Cp = KB * 32;
  _Float16* ph = xh + ((size_t)b * NN + n) * Cp;
  _Float16* pl = xl + ((size_t)b * NN + n) * Cp;
  float s = 0.f;
  for (int kb = 0; kb < KB; kb++) {
    for (int g = 0; g < 4; g++) {
      v8h hv, lv;
#pragma unroll
      for (int j = 0; j < 8; j++) {
        int c = kb * 32 + g * 8 + j;
        float v = (c < C) ? xb[(size_t)c * NN + n] : 0.f;
        _Float16 h = (_Float16)v;
        hv[j] = h;
        lv[j] = (_Float16)(v - (float)h);
        s = fmaf(v, v, s);
      }
      *(v8h*)(ph + kb * 32 + g * 8) = hv;
      *(v8h*)(pl + kb * 32 + g * 8) = lv;
    }
  }
  xx[b * NN + n] = s;
}

// ---------------- tile scorer: 32 queries (2 A-tiles) x 16 candidates ----------
template<int KB>
__device__ __forceinline__ void tile_scores2(const v8h (&Bh)[KB], const v8h (&Bl)[KB],
    const v8h (&Ah)[2][KB], const v8h (&Al)[2][KB], float xv, v4f (&out)[2])
{
#pragma unroll
  for (int a = 0; a < 2; a++) {
    v4f a0 = {0.f, 0.f, 0.f, 0.f};
    v4f a1 = {0.f, 0.f, 0.f, 0.f};
#pragma unroll
    for (int kb = 0; kb < KB; kb++) {
      v4f& acc = (kb & 1) ? a1 : a0;
      acc = __builtin_amdgcn_mfma_f32_16x16x32_f16(Ah[a][kb], Bh[kb], acc, 0, 0, 0);
      acc = __builtin_amdgcn_mfma_f32_16x16x32_f16(Ah[a][kb], Bl[kb], acc, 0, 0, 0);
      acc = __builtin_amdgcn_mfma_f32_16x16x32_f16(Al[a][kb], Bh[kb], acc, 0, 0, 0);
    }
    v4f s = a0 + a1;
#pragma unroll
    for (int j = 0; j < 4; j++) out[a][j] = s[j] - 0.5f * xv;
  }
}

// ---------------- kNN stage 1: 32 q/wave, 2 waves/SIMD, 2-deep ring -----------
// Pass 1: 32 group-maxima/query -> tau = rank-19 (provably <= true 20th score).
// Pass 2: bitwise-identical rescore; survivors >= tau -> global list (cap 64).
template<int KB>
__global__ __launch_bounds__(256, 2) void knn3(
    const _Float16* __restrict__ xh, const _Float16* __restrict__ xl,
    const float* __restrict__ xxg, ull* __restrict__ slistG, int* __restrict__ cntG)
{
  __shared__ float gmL[128][33];
  __shared__ float tauL[128];
  __shared__ int scnt[128];

  const int t = threadIdx.x;
  const int lane = t & 63;
  const int wave = t >> 6;
  const int col = lane & 15;
  const int quad = lane >> 4;
  const int quad8 = quad * 8;
  const int b = blockIdx.x >> 1;
  const int chunk = blockIdx.x & 1;
  const int qg = blockIdx.y;
  const int Cp = KB * 32;
  const int cb = chunk * 1024;
  const _Float16* xhb = xh + (size_t)b * NN * Cp;
  const _Float16* xlb = xl + (size_t)b * NN * Cp;
  const float* xxb = xxg + b * NN;

  v8h Ah[2][KB], Al[2][KB];
  const int qw = qg * 128 + wave * 32;
#pragma unroll
  for (int a = 0; a < 2; a++) {
    const _Float16* pa = xhb + (size_t)(qw + a * 16 + col) * Cp + quad8;
    const _Float16* pb = xlb + (size_t)(qw + a * 16 + col) * Cp + quad8;
#pragma unroll
    for (int kb = 0; kb < KB; kb++) {
      Ah[a][kb] = *(const v8h*)(pa + kb * 32);
      Al[a][kb] = *(const v8h*)(pb + kb * 32);
    }
  }

  v8h Bh[2][KB], Bl[2][KB];
  float xvb[2];
  auto loadB = [&](int slot, int tt) {
    int t2 = tt < 63 ? tt : 63;
    int n = cb + t2 * 16 + col;
    const _Float16* pb = xhb + (size_t)n * Cp + quad8;
    const _Float16* pl = xlb + (size_t)n * Cp + quad8;
#pragma unroll
    for (int kb = 0; kb < KB; kb++) {
      Bh[slot][kb] = *(const v8h*)(pb + kb * 32);
      Bl[slot][kb] = *(const v8h*)(pl + kb * 32);
    }
    xvb[slot] = xxb[n];
  };

  // ---- pass 1: group maxima (16 cols x 2 tile-parities = 32 groups/query) ----
  float gm[2][8];
#pragma unroll
  for (int a = 0; a < 2; a++)
#pragma unroll
    for (int j = 0; j < 8; j++) gm[a][j] = -3.4e38f;

  loadB(0, 0);
  for (int tt = 0; tt < 64; tt += 2) {
    loadB(1, tt + 1);
    {
      v4f out[2];
      tile_scores2<KB>(Bh[0], Bl[0], Ah, Al, xvb[0], out);
#pragma unroll
      for (int a = 0; a < 2; a++)
#pragma unroll
        for (int j = 0; j < 4; j++) gm[a][j * 2] = fmaxf(gm[a][j * 2], out[a][j]);
    }
    loadB(0, tt + 2);
    {
      v4f out[2];
      tile_scores2<KB>(Bh[1], Bl[1], Ah, Al, xvb[1], out);
#pragma unroll
      for (int a = 0; a < 2; a++)
#pragma unroll
        for (int j = 0; j < 4; j++) gm[a][j * 2 + 1] = fmaxf(gm[a][j * 2 + 1], out[a][j]);
    }
  }

  // wave-private LDS rows -> no barrier, just lgkm drain
#pragma unroll
  for (int a = 0; a < 2; a++)
#pragma unroll
    for (int j = 0; j < 4; j++) {
      int qi = wave * 32 + a * 16 + quad * 4 + j;
      gmL[qi][col * 2 + 0] = gm[a][j * 2 + 0];
      gmL[qi][col * 2 + 1] = gm[a][j * 2 + 1];
    }
  if (lane < 32) scnt[wave * 32 + lane] = 0;
  asm volatile("s_waitcnt lgkmcnt(0)" ::: "memory");

  // tau = rank-19 of 32 group maxima
  for (int r = 0; r < 16; r++) {
    const int q = wave * 32 + r * 2 + (lane >> 5);
    const int idx = lane & 31;
    float v = gmL[q][idx];
#pragma unroll
    for (int kk = 2; kk <= 32; kk <<= 1) {
#pragma unroll
      for (int m = kk >> 1; m >= 1; m >>= 1) {
        float o = shflx_f(v, m);
        bool keepmax = ((idx & kk) == 0) == ((idx & m) == 0);
        v = keepmax ? fmaxf(v, o) : fminf(v, o);
      }
    }
    if (idx == 19) tauL[q] = v;
  }
  asm volatile("s_waitcnt lgkmcnt(0)" ::: "memory");

  float tq[2][4];
#pragma unroll
  for (int a = 0; a < 2; a++)
#pragma unroll
    for (int j = 0; j < 4; j++) tq[a][j] = tauL[wave * 32 + a * 16 + quad * 4 + j];

  // ---- pass 2: bitwise-identical rescore, compact survivors >= tau ----
  ull* slB = slistG + (((size_t)b * NN + qg * 128) * 2 + chunk) * 64;
  loadB(0, 0);
  for (int tt = 0; tt < 64; tt += 2) {
    loadB(1, tt + 1);
    for (int s = 0; s < 2; s++) {
      v4f out[2];
      tile_scores2<KB>(s ? Bh[1] : Bh[0], s ? Bl[1] : Bl[0], Ah, Al, xvb[s], out);
      int n = cb + (tt + s) * 16 + col;
#pragma unroll
      for (int a = 0; a < 2; a++)
#pragma unroll
        for (int j = 0; j < 4; j++) {
          float sc = out[a][j];
          if (sc >= tq[a][j]) {
            int qi = wave * 32 + a * 16 + quad * 4 + j;
            int pos = atomicAdd(&scnt[qi], 1);
            if (pos < 64) slB[(size_t)qi * 128 + pos] = packkey(sc, n);
          }
        }
      if (s == 0) loadB(0, tt + 2);
    }
  }
  asm volatile("s_waitcnt lgkmcnt(0)" ::: "memory");
  if (lane < 32)
    cntG[((size_t)b * NN + qg * 128 + wave * 32 + lane) * 2 + chunk] = scnt[wave * 32 + lane];
}

// ---------------- kNN stage 2: merge 2 chunk survivor lists -> top-20 --------
__global__ __launch_bounds__(256) void knn_merge(const ull* __restrict__ slistG,
    const int* __restrict__ cntG, const _Float16* __restrict__ xh,
    const _Float16* __restrict__ xl, const float* __restrict__ xxg,
    int* __restrict__ idxout, int Cp, int C)
{
  const int lane = threadIdx.x & 63, wave = threadIdx.x >> 6;
  const int b = blockIdx.y;
  const int q = blockIdx.x * 4 + wave;
  const int c0 = cntG[((size_t)b * NN + q) * 2 + 0];
  const int c1 = cntG[((size_t)b * NN + q) * 2 + 1];
  int* op = idxout + ((size_t)b * NN + q) * KK;

  if (c0 <= 64 && c1 <= 64) {
    const ull* s0 = slistG + ((size_t)b * NN + q) * 128;
    const int total = c0 + c1;
    ull e0 = 0, e1 = 0;
    int p0 = lane, p1 = lane + 64;
    if (p0 < total) e0 = (p0 < c0) ? s0[p0] : s0[64 + p0 - c0];
    if (p1 < total) e1 = (p1 < c0) ? s0[p1] : s0[64 + p1 - c0];
    for (int s = 0; s < KK; s++) {
      ull m = e0 > e1 ? e0 : e1;
      ull g = m;
#pragma unroll
      for (int d = 1; d < 64; d <<= 1) { ull o = shflx_u64(g, d); g = o > g ? o : g; }
      if (lane == 0) op[s] = 2047 - (int)(g & 0xFFFFFFFFu);
      if (e0 == g) e0 = 0; else if (e1 == g) e1 = 0;
    }
  } else {
    // exact fallback (survivor cap overflow — expected never): full fp32 rescan
    const _Float16* qh = xh + ((size_t)b * NN + q) * Cp;
    const _Float16* ql = xl + ((size_t)b * NN + q) * Cp;
    const float* xxb = xxg + b * NN;
    float sc[32];
#pragma unroll
    for (int i = 0; i < 32; i++) sc[i] = -0.5f * xxb[lane + 64 * i];
    for (int c = 0; c < C; c++) {
      float qv = (float)qh[c] + (float)ql[c];
      for (int i = 0; i < 32; i++) {
        int n = lane + 64 * i;
        float bv = (float)xh[((size_t)b * NN + n) * Cp + c] + (float)xl[((size_t)b * NN + n) * Cp + c];
        sc[i] = fmaf(qv, bv, sc[i]);
      }
    }
    for (int s = 0; s < KK; s++) {
      ull m = 0; int mi = -1;
      for (int i = 0; i < 32; i++) {
        ull k = packkey(sc[i], lane + 64 * i);
        if (k > m) { m = k; mi = i; }
      }
      ull g = m;
#pragma unroll
      for (int d = 1; d < 64; d <<= 1) { ull o = shflx_u64(g, d); g = o > g ? o : g; }
      if (lane == 0) op[s] = 2047 - (int)(g & 0xFFFFFFFFu);
      if (m == g && mi >= 0) sc[mi] = -3.4e38f;
    }
  }
}

// ---------------- weight converts ----------------
__global__ __launch_bounds__(256) void wcvt_uv(const float* __restrict__ w,
    _Float16* __restrict__ wuh, _Float16* __restrict__ wul,
    _Float16* __restrict__ wvh, _Float16* __restrict__ wvl, int C, int Cp, int O)
{
  int idx = blockIdx.x * 256 + threadIdx.x;
  if (idx >= O * Cp) return;
  int o = idx / Cp, c = idx - o * Cp;
  float a = 0.f, bv = 0.f;
  if (c < C) { a = w[o * 2 * C + c]; bv = w[o * 2 * C + C + c]; }
  float v = bv - a;
  _Float16 ah = (_Float16)a; wuh[idx] = ah; wul[idx] = (_Float16)(a - (float)ah);
  _Float16 vh = (_Float16)v; wvh[idx] = vh; wvl[idx] = (_Float16)(v - (float)vh);
}

__global__ __launch_bounds__(256) void w5cvt(const float* __restrict__ w5,
    _Float16* __restrict__ w5h, _Float16* __restrict__ w5l)
{
  int idx = blockIdx.x * 256 + threadIdx.x;
  float v = w5[idx];
  _Float16 h = (_Float16)v;
  w5h[idx] = h;
  w5l[idx] = (_Float16)(v - (float)h);
}

// ---------------- xcat fp32 [b][c][n] -> f16 hi/lo fragments [b][kc][n][32] ----
__global__ __launch_bounds__(256) void y5cvt_kernel(const float* __restrict__ xcat,
    _Float16* __restrict__ xh, _Float16* __restrict__ xl)
{
  const int b = blockIdx.y;
  const int n = blockIdx.x * 256 + threadIdx.x;
  for (int kc = blockIdx.z * 4; kc < blockIdx.z * 4 + 4; kc++) {
    v8h h[4], l[4];
#pragma unroll
    for (int g = 0; g < 4; g++)
#pragma unroll
      for (int j = 0; j < 8; j++) {
        float v = xcat[((size_t)b * 512 + kc * 32 + g * 8 + j) * NN + n];
        _Float16 hh = (_Float16)v;
        h[g][j] = hh;
        l[g][j] = (_Float16)(v - (float)hh);
      }
    size_t base = (((size_t)b * 16 + kc) * NN + n) * 32;
#pragma unroll
    for (int g = 0; g < 4; g++) {
      *(v8h*)(xh + base + g * 8) = h[g];
      *(v8h*)(xl + base + g * 8) = l[g];
    }
  }
}

// ---------------- y5 = w5 * xcat via MFMA (f16 hi/lo 3-product) ----------------
__global__ __launch_bounds__(256) void y5_mfma(const _Float16* __restrict__ w5h,
    const _Float16* __restrict__ w5l, const _Float16* __restrict__ xh,
    const _Float16* __restrict__ xl, float* __restrict__ y5)
{
  const int lane = threadIdx.x & 63, wave = threadIdx.x >> 6;
  const int col = lane & 15, quad = lane >> 4, quad8 = quad * 8;
  const int b = blockIdx.z;
  const int o0 = blockIdx.x * 256 + wave * 64;
  const int nb0 = blockIdx.y * 128;
  v4f acc[4][8];
#pragma unroll
  for (int a = 0; a < 4; a++)
#pragma unroll
    for (int t = 0; t < 8; t++) acc[a][t] = {0.f, 0.f, 0.f, 0.f};

  for (int kc = 0; kc < 16; kc++) {
    v8h Ah[4], Al[4];
#pragma unroll
    for (int a = 0; a < 4; a++) {
      size_t off = (size_t)(o0 + a * 16 + col) * 512 + kc * 32 + quad8;
      Ah[a] = *(const v8h*)(w5h + off);
      Al[a] = *(const v8h*)(w5l + off);
    }
#pragma unroll
    for (int t = 0; t < 8; t++) {
      int n = nb0 + t * 16 + col;
      size_t boff = (((size_t)b * 16 + kc) * NN + n) * 32 + quad8;
      v8h Bh = *(const v8h*)(xh + boff);
      v8h Bl = *(const v8h*)(xl + boff);
#pragma unroll
      for (int a = 0; a < 4; a++) {
        acc[a][t] = __builtin_amdgcn_mfma_f32_16x16x32_f16(Ah[a], Bh, acc[a][t], 0, 0, 0);
        acc[a][t] = __builtin_amdgcn_mfma_f32_16x16x32_f16(Ah[a], Bl, acc[a][t], 0, 0, 0);
        acc[a][t] = __builtin_amdgcn_mfma_f32_16x16x32_f16(Al[a], Bh, acc[a][t], 0, 0, 0);
      }
    }
  }
#pragma unroll
  for (int a = 0; a < 4; a++)
#pragma unroll
    for (int t = 0; t < 8; t++)
#pragma unroll
      for (int j = 0; j < 4; j++)
        y5[((size_t)b * 512 + o0 + a * 16 + quad * 4 + j) * NN + nb0 + t * 16 + col] = acc[a][t][j];
}

// ---------------- U/V chunk (64 out-ch) via MFMA: U = Wa*x, V = (Wb-Wa)*x ------
__global__ __launch_bounds__(256) void uv_mfma(const _Float16* __restrict__ wuh,
    const _Float16* __restrict__ wul, const _Float16* __restrict__ wvh,
    const _Float16* __restrict__ wvl, const _Float16* __restrict__ xh,
    const _Float16* __restrict__ xl, float* __restrict__ Uc, float* __restrict__ Vc,
    int Cp)
{
  const int lane = threadIdx.x & 63, wave = threadIdx.x >> 6;
  const int col = lane & 15, quad = lane >> 4, quad8 = quad * 8;
  const int b = blockIdx.z;
  const int o0 = blockIdx.x * 32;           // chunk-local out channel base
  const int nb0 = blockIdx.y * 512 + wave * 128;
  v4f aU[2][8], aV[2][8];
#pragma unroll
  for (int a = 0; a < 2; a++)
#pragma unroll
    for (int t = 0; t < 8; t++) { aU[a][t] = {0.f,0.f,0.f,0.f}; aV[a][t] = {0.f,0.f,0.f,0.f}; }

  const int KBr = Cp >> 5;
  for (int kb = 0; kb < KBr; kb++) {
    v8h Uh[2], Ul[2], Vh[2], Vl[2];
#pragma unroll
    for (int a = 0; a < 2; a++) {
      size_t off = (size_t)(o0 + a * 16 + col) * Cp + kb * 32 + quad8;
      Uh[a] = *(const v8h*)(wuh + off);
      Ul[a] = *(const v8h*)(wul + off);
      Vh[a] = *(const v8h*)(wvh + off);
      Vl[a] = *(const v8h*)(wvl + off);
    }
#pragma unroll
    for (int t = 0; t < 8; t++) {
      int n = nb0 + t * 16 + col;
      size_t boff = ((size_t)b * NN + n) * Cp + kb * 32 + quad8;
      v8h Bh = *(const v8h*)(xh + boff);
      v8h Bl = *(const v8h*)(xl + boff);
#pragma unroll
      for (int a = 0; a < 2; a++) {
        aU[a][t] = __builtin_amdgcn_mfma_f32_16x16x32_f16(Uh[a], Bh, aU[a][t], 0, 0, 0);
        aU[a][t] = __builtin_amdgcn_mfma_f32_16x16x32_f16(Uh[a], Bl, aU[a][t], 0, 0, 0);
        aU[a][t] = __builtin_amdgcn_mfma_f32_16x16x32_f16(Ul[a], Bh, aU[a][t], 0, 0, 0);
        aV[a][t] = __builtin_amdgcn_mfma_f32_16x16x32_f16(Vh[a], Bh, aV[a][t], 0, 0, 0);
        aV[a][t] = __builtin_amdgcn_mfma_f32_16x16x32_f16(Vh[a], Bl, aV[a][t], 0, 0, 0);
        aV[a][t] = __builtin_amdgcn_mfma_f32_16x16x32_f16(Vl[a], Bh, aV[a][t], 0, 0, 0);
      }
    }
  }
#pragma unroll
  for (int a = 0; a < 2; a++)
#pragma unroll
    for (int t = 0; t < 8; t++)
#pragma unroll
      for (int j = 0; j < 4; j++) {
        size_t base = ((size_t)b * 64 + o0 + a * 16 + quad * 4 + j) * NN + nb0 + t * 16 + col;
        Uc[base] = aU[a][t][j];
        Vc[base] = aV[a][t][j];
      }
}

// ---------------- edge aggregation: 2-pass stats + normalized max-over-k -------
// Uc/Vc are chunk-local [b][64][NN]; xo pre-offset to the chunk's first channel.
__global__ __launch_bounds__(256) void edge_kernel(const float* __restrict__ Uc,
    const float* __restrict__ Vc, const int* __restrict__ idx,
    float* __restrict__ xo)
{
  __shared__ float Ur[4 * 2052];   // +4 pad breaks the i-stride bank collision
  __shared__ float red[8][4];
  __shared__ float smv[8];
  const int b = blockIdx.y, o0 = blockIdx.x * 4;
  const int t = threadIdx.x, lane = t & 63, wave = t >> 6;
  for (int r = 0; r < 4; r++)
    for (int i = t; i < NN; i += 256)
      Ur[r * 2052 + i] = Uc[((size_t)b * 64 + o0 + r) * NN + i];
  __syncthreads();
  const float* Vb = Vc + ((size_t)b * 64 + o0) * NN;
  const int* ib = idx + (size_t)b * NN * KK;
  float s0 = 0, s1 = 0, s2 = 0, s3 = 0, c0 = 0, c1 = 0, c2 = 0, c3 = 0;
  for (int n = t; n < NN; n += 256) {
    float v0 = Vb[n], v1 = Vb[NN + n], v2 = Vb[2 * NN + n], v3 = Vb[3 * NN + n];
    const int* ip = ib + (size_t)n * KK;
#pragma unroll
    for (int j = 0; j < KK; j++) {
      int m = ip[j];
      float y0 = Ur[m] + v0, y1 = Ur[2052 + m] + v1;
      float y2 = Ur[4104 + m] + v2, y3 = Ur[6156 + m] + v3;
      s0 += y0; c0 = fmaf(y0, y0, c0);
      s1 += y1; c1 = fmaf(y1, y1, c1);
      s2 += y2; c2 = fmaf(y2, y2, c2);
      s3 += y3; c3 = fmaf(y3, y3, c3);
    }
  }
  float sa[4] = { s0, s1, s2, s3 }, ca[4] = { c0, c1, c2, c3 };
#pragma unroll
  for (int r = 0; r < 4; r++) {
    float a = sa[r], c = ca[r];
#pragma unroll
    for (int d = 1; d < 64; d <<= 1) { a += shflx_f(a, d); c += shflx_f(c, d); }
    if (lane == 0) { red[r][wave] = a; red[4 + r][wave] = c; }
  }
  __syncthreads();
  if (t < 4) {
    float a = red[t][0] + red[t][1] + red[t][2] + red[t][3];
    float c = red[4 + t][0] + red[4 + t][1] + red[4 + t][2] + red[4 + t][3];
    const float inv = 1.f / (float)(NN * KK);
    float mu = a * inv;
    float var = fmaxf(c * inv - mu * mu, 0.f);
    smv[t] = mu;
    smv[4 + t] = rsqrtf(var + EPSF);
  }
  __syncthreads();
  const float mu0 = smv[0], mu1 = smv[1], mu2 = smv[2], mu3 = smv[3];
  const float i0 = smv[4], i1 = smv[5], i2 = smv[6], i3 = smv[7];
  for (int n = t; n < NN; n += 256) {
    float v0 = Vb[n], v1 = Vb[NN + n], v2 = Vb[2 * NN + n], v3 = Vb[3 * NN + n];
    const int* ip = ib + (size_t)n * KK;
    float m0 = -3.4e38f, m1 = m0, m2 = m0, m3 = m0;
#pragma unroll
    for (int j = 0; j < KK; j++) {
      int m = ip[j];
      m0 = fmaxf(m0, Ur[m] + v0);
      m1 = fmaxf(m1, Ur[2052 + m] + v1);
      m2 = fmaxf(m2, Ur[4104 + m] + v2);
      m3 = fmaxf(m3, Ur[6156 + m] + v3);
    }
    float z;  // leaky-relu commutes with max (inv > 0)
    z = (m0 - mu0) * i0; xo[((size_t)b * 512 + o0 + 0) * NN + n] = z >= 0.f ? z : 0.2f * z;
    z = (m1 - mu1) * i1; xo[((size_t)b * 512 + o0 + 1) * NN + n] = z >= 0.f ? z : 0.2f * z;
    z = (m2 - mu2) * i2; xo[((size_t)b * 512 + o0 + 2) * NN + n] = z >= 0.f ? z : 0.2f * z;
    z = (m3 - mu3) * i3; xo[((size_t)b * 512 + o0 + 3) * NN + n] = z >= 0.f ? z : 0.2f * z;
  }
}

__global__ __launch_bounds__(256) void bn5stat_kernel(const float* __restrict__ y5,
    float* __restrict__ bn5) {
  __shared__ float rs[4], rq[4];
  const int o = blockIdx.x, t = threadIdx.x, lane = t & 63, wave = t >> 6;
  float s = 0.f, q = 0.f;
  for (int b = 0; b < NB; b++) {
    const float* p = y5 + ((size_t)b * 512 + o) * NN;
    for (int n = t; n < NN; n += 256) { float v = p[n]; s += v; q = fmaf(v, v, q); }
  }
#pragma unroll
  for (int d = 1; d < 64; d <<= 1) { s += shflx_f(s, d); q += shflx_f(q, d); }
  if (lane == 0) { rs[wave] = s; rq[wave] = q; }
  __syncthreads();
  if (t == 0) {
    float S = rs[0] + rs[1] + rs[2] + rs[3];
    float Q = rq[0] + rq[1] + rq[2] + rq[3];
    const float inv = 1.f / (float)(NB * NN);
    float mu = S * inv;
    float var = fmaxf(Q * inv - mu * mu, 0.f);
    bn5[o] = mu;
    bn5[512 + o] = rsqrtf(var + EPSF);
  }
}

__global__ __launch_bounds__(256) void final_kernel(const float* __restrict__ y5,
    const float* __restrict__ bn5, const float* __restrict__ gamma,
    const float* __restrict__ beta, float* __restrict__ out)
{
  __shared__ float rm[4], rs[4];
  const int o = blockIdx.x, b = blockIdx.y, t = threadIdx.x, lane = t & 63, wave = t >> 6;
  const float mu = bn5[o], iv = bn5[512 + o], g = gamma[o], be = beta[o];
  const float* p = y5 + ((size_t)b * 512 + o) * NN;
  float mx = -3.4e38f, sm = 0.f;
  for (int n = t; n < NN; n += 256) {
    float z = (p[n] - mu) * iv;
    z = z * g + be;
    z = (z >= 0.f) ? z : 0.2f * z;
    mx = fmaxf(mx, z);
    sm += z;
  }
#pragma unroll
  for (int d = 1; d < 64; d <<= 1) { mx = fmaxf(mx, shflx_f(mx, d)); sm += shflx_f(sm, d); }
  if (lane == 0) { rm[wave] = mx; rs[wave] = sm; }
  __syncthreads();
  if (t == 0) {
    float M = fmaxf(fmaxf(rm[0], rm[1]), fmaxf(rm[2], rm[3]));
    float S = rs[0] + rs[1] + rs[2] + rs[3];
    out[(size_t)b * 1024 + o] = M;
    out[(size_t)b * 1024 + 512 + o] = S * (1.f / NN);
  }
}

extern "C" void kernel_launch(void* const* d_in, const int* in_sizes, int n_in,
                              void* d_out, int out_size, void* d_ws, size_t ws_size,
                              hipStream_t stream)
{
  (void)in_sizes; (void)n_in; (void)out_size; (void)ws_size;
  const float* x  = (const float*)d_in[0];
  const float* w1 = (const float*)d_in[1];
  const float* w2 = (const float*)d_in[2];
  const float* w3 = (const float*)d_in[3];
  const float* w4 = (const float*)d_in[4];
  const float* w5 = (const float*)d_in[5];
  const float* g5 = (const float*)d_in[6];
  const float* b5 = (const float*)d_in[7];
  float* out = (float*)d_out;

  // workspace layout (round-6 proven 137 MB layout)
  float* ws   = (float*)d_ws;
  float* xcat = ws;                         // 16*512*2048 fp32 (67.1 MB)
  float* Ub   = xcat + 16777216;            // 8.39M floats (33.5 MB)
  float* Vb   = Ub + 8388608;               // 8.39M floats (33.5 MB)
  int*   idxb = (int*)(Vb + 8388608);       // 16*2048*20 ints
  float* xxb  = (float*)(idxb + 655360);    // 32768 floats
  float* bn5  = xxb + 32768;                // 1024

  // Vb carve-up: xth | xtl | cntb | Vc(chunk V) | weight stash
  _Float16* xth = (_Float16*)Vb;                       // 4.19M halves
  _Float16* xtl = xth + 4194304;                       // 4.19M halves
  int* cntb = (int*)(Vb + 4194304);                    // 65536 ints
  float* Vc = Vb + 4259840;                            // 2.10M floats (64ch chunk)
  _Float16* wuh = (_Float16*)(Vb + 6356992);           // 4 x 32768 halves
  _Float16* wul = wuh + 32768;
  _Float16* wvh = wul + 32768;
  _Float16* wvl = wvh + 32768;

  ull* slist = (ull*)Ub;       // survivor lists alias Ub (dead after merge)
  float* Uc = Ub;              // chunk U buffer (64ch) at Ub head

  _Float16* w5h = (_Float16*)idxb;   // idx dead after last edge
  _Float16* w5l = w5h + 262144;
  _Float16* xcfh = (_Float16*)Ub;
  _Float16* xcfl = (_Float16*)Vb;
  float* y5 = xcat;

  struct Lyr { const float* xin; long bstride; int C, KB, O, coff; const float* w; };
  const Lyr L[4] = {
    { x,              3L * NN,   3,   1, 64,  0,   w1 },
    { xcat,           512L * NN, 64,  2, 64,  64,  w2 },
    { xcat + 64 * NN, 512L * NN, 64,  2, 128, 128, w3 },
    { xcat + 128 * NN,512L * NN, 128, 4, 256, 256, w4 },
  };

  for (int l = 0; l < 4; l++) {
    const int Cp = L[l].KB * 32, O = L[l].O, C = L[l].C;
    prep_kernel<<<dim3(NN / 256, NB), 256, 0, stream>>>(L[l].xin, xth, xtl, xxb,
                                                        C, L[l].KB, L[l].bstride);
    switch (L[l].KB) {
      case 1: knn3<1><<<dim3(NB * 2, NN / 128), 256, 0, stream>>>(xth, xtl, xxb, slist, cntb); break;
      case 2: knn3<2><<<dim3(NB * 2, NN / 128), 256, 0, stream>>>(xth, xtl, xxb, slist, cntb); break;
      default: knn3<4><<<dim3(NB * 2, NN / 128), 256, 0, stream>>>(xth, xtl, xxb, slist, cntb); break;
    }
    knn_merge<<<dim3(NN / 4, NB), 256, 0, stream>>>(slist, cntb, xth, xtl, xxb, idxb,
                                                    Cp, C);
    wcvt_uv<<<(O * Cp + 255) / 256, 256, 0, stream>>>(L[l].w, wuh, wul, wvh, wvl,
                                                      C, Cp, O);
    for (int c0 = 0; c0 < O; c0 += 64) {
      uv_mfma<<<dim3(2, NN / 512, NB), 256, 0, stream>>>(
          wuh + (size_t)c0 * Cp, wul + (size_t)c0 * Cp,
          wvh + (size_t)c0 * Cp, wvl + (size_t)c0 * Cp,
          xth, xtl, Uc, Vc, Cp);
      edge_kernel<<<dim3(16, NB), 256, 0, stream>>>(Uc, Vc, idxb,
          xcat + (size_t)(L[l].coff + c0) * NN);
    }
  }
  w5cvt<<<1024, 256, 0, stream>>>(w5, w5h, w5l);
  y5cvt_kernel<<<dim3(NN / 256, NB, 4), 256, 0, stream>>>(xcat, xcfh, xcfl);
  y5_mfma<<<dim3(2, NN / 128, NB), 256, 0, stream>>>(w5h, w5l, xcfh, xcfl, y5);
  bn5stat_kernel<<<512, 256, 0, stream>>>(y5, bn5);
  final_kernel<<<dim3(512, NB), 256, 0, stream>>>(y5, bn5, g5, b5, out);
}

// Round 11
// 1636.290 us; speedup vs baseline: 1.5684x; 1.0650x over previous
//
#include <hip/hip_runtime.h>

#define NN 2048      // points
#define NB 16        // batch
#define KK 20        // k neighbors
#define EPSF 1e-5f

typedef unsigned long long ull;
typedef _Float16 v8h __attribute__((ext_vector_type(8)));
typedef float v4f __attribute__((ext_vector_type(4)));

__device__ __forceinline__ float shflx_f(float v, int m) { return __shfl_xor(v, m, 64); }
__device__ __forceinline__ ull shflx_u64(ull v, int m) {
  int lo = __shfl_xor((int)(unsigned)v, m, 64);
  int hi = __shfl_xor((int)(unsigned)(v >> 32), m, 64);
  return (((ull)(unsigned)hi) << 32) | (unsigned)lo;
}
__device__ __forceinline__ ull packkey(float s, int n) {
  unsigned u = __float_as_uint(s);
  u = (u & 0x80000000u) ? ~u : (u | 0x80000000u);
  return (((ull)u) << 32) | (unsigned)(2047 - n);   // ties -> lowest index wins under max
}

// ---------------- prep: x[C][N] fp32 -> fragment-ready f16 hi/lo [n][Cp] + xx ----
__global__ __launch_bounds__(256) void prep_kernel(const float* __restrict__ x,
    _Float16* __restrict__ xh, _Float16* __restrict__ xl, float* __restrict__ xx,
    int C, int KB, long bstride)
{
  const int b = blockIdx.y;
  const int n = blockIdx.x * 256 + threadIdx.x;
  const float* xb = x + (size_t)b * bstride;
  const int Cp = KB * 32;
  _Float16* ph = xh + ((size_t)b * NN + n) * Cp;
  _Float16* pl = xl + ((size_t)b * NN + n) * Cp;
  float s = 0.f;
  for (int kb = 0; kb < KB; kb++) {
    for (int g = 0; g < 4; g++) {
      v8h hv, lv;
#pragma unroll
      for (int j = 0; j < 8; j++) {
        int c = kb * 32 + g * 8 + j;
        float v = (c < C) ? xb[(size_t)c * NN + n] : 0.f;
        _Float16 h = (_Float16)v;
        hv[j] = h;
        lv[j] = (_Float16)(v - (float)h);
        s = fmaf(v, v, s);
      }
      *(v8h*)(ph + kb * 32 + g * 8) = hv;
      *(v8h*)(pl + kb * 32 + g * 8) = lv;
    }
  }
  xx[b * NN + n] = s;
}

// ---------------- tile scorer: 64 queries (4 A-tiles) x 16 candidates ----------
template<int KB>
__device__ __forceinline__ void tile_scores(const v8h (&Bh)[KB], const v8h (&Bl)[KB],
    const v8h (&Ah)[4][KB], const v8h (&Al)[4][KB], float xv, v4f (&out)[4])
{
#pragma unroll
  for (int a = 0; a < 4; a++) {
    v4f a0 = {0.f, 0.f, 0.f, 0.f};
    v4f a1 = {0.f, 0.f, 0.f, 0.f};
#pragma unroll
    for (int kb = 0; kb < KB; kb++) {
      v4f& acc = (kb & 1) ? a1 : a0;
      acc = __builtin_amdgcn_mfma_f32_16x16x32_f16(Ah[a][kb], Bh[kb], acc, 0, 0, 0);
      acc = __builtin_amdgcn_mfma_f32_16x16x32_f16(Ah[a][kb], Bl[kb], acc, 0, 0, 0);
      acc = __builtin_amdgcn_mfma_f32_16x16x32_f16(Al[a][kb], Bh[kb], acc, 0, 0, 0);
    }
    v4f s = a0 + a1;
#pragma unroll
    for (int j = 0; j < 4; j++) out[a][j] = s[j] - 0.5f * xv;
  }
}

// ---------------- kNN stage 1: 64 q/wave, 2 chunks, 2-deep ring (proven 208us) --
template<int KB>
__global__ __launch_bounds__(256, 1) void knn2(
    const _Float16* __restrict__ xh, const _Float16* __restrict__ xl,
    const float* __restrict__ xxg, ull* __restrict__ slistG, int* __restrict__ cntG)
{
  __shared__ float gmL[256][33];
  __shared__ float tauL[256];
  __shared__ int scnt[256];

  const int t = threadIdx.x;
  const int lane = t & 63;
  const int wave = t >> 6;
  const int col = lane & 15;
  const int quad = lane >> 4;
  const int quad8 = quad * 8;
  const int b = blockIdx.x >> 1;
  const int chunk = blockIdx.x & 1;
  const int qg = blockIdx.y;
  const int Cp = KB * 32;
  const int cb = chunk * 1024;
  const _Float16* xhb = xh + (size_t)b * NN * Cp;
  const _Float16* xlb = xl + (size_t)b * NN * Cp;
  const float* xxb = xxg + b * NN;

  v8h Ah[4][KB], Al[4][KB];
  const int qw = qg * 256 + wave * 64;
#pragma unroll
  for (int a = 0; a < 4; a++) {
    const _Float16* pa = xhb + (size_t)(qw + a * 16 + col) * Cp + quad8;
    const _Float16* pb = xlb + (size_t)(qw + a * 16 + col) * Cp + quad8;
#pragma unroll
    for (int kb = 0; kb < KB; kb++) {
      Ah[a][kb] = *(const v8h*)(pa + kb * 32);
      Al[a][kb] = *(const v8h*)(pb + kb * 32);
    }
  }

  v8h Bh[2][KB], Bl[2][KB];
  float xvb[2];
  auto loadB = [&](int slot, int tt) {
    int t2 = tt < 63 ? tt : 63;
    int n = cb + t2 * 16 + col;
    const _Float16* pb = xhb + (size_t)n * Cp + quad8;
    const _Float16* pl = xlb + (size_t)n * Cp + quad8;
#pragma unroll
    for (int kb = 0; kb < KB; kb++) {
      Bh[slot][kb] = *(const v8h*)(pb + kb * 32);
      Bl[slot][kb] = *(const v8h*)(pl + kb * 32);
    }
    xvb[slot] = xxb[n];
  };

  // ---- pass 1: group maxima (16 cols x 2 tile-parities = 32 groups/query) ----
  float gm[4][8];
#pragma unroll
  for (int a = 0; a < 4; a++)
#pragma unroll
    for (int j = 0; j < 8; j++) gm[a][j] = -3.4e38f;

  loadB(0, 0);
  for (int tt = 0; tt < 64; tt += 2) {
    loadB(1, tt + 1);
    {
      v4f out[4];
      tile_scores<KB>(Bh[0], Bl[0], Ah, Al, xvb[0], out);
#pragma unroll
      for (int a = 0; a < 4; a++)
#pragma unroll
        for (int j = 0; j < 4; j++) gm[a][j * 2] = fmaxf(gm[a][j * 2], out[a][j]);
    }
    loadB(0, tt + 2);
    {
      v4f out[4];
      tile_scores<KB>(Bh[1], Bl[1], Ah, Al, xvb[1], out);
#pragma unroll
      for (int a = 0; a < 4; a++)
#pragma unroll
        for (int j = 0; j < 4; j++) gm[a][j * 2 + 1] = fmaxf(gm[a][j * 2 + 1], out[a][j]);
    }
  }

#pragma unroll
  for (int a = 0; a < 4; a++)
#pragma unroll
    for (int j = 0; j < 4; j++) {
      int qi = wave * 64 + a * 16 + quad * 4 + j;
      gmL[qi][col * 2 + 0] = gm[a][j * 2 + 0];
      gmL[qi][col * 2 + 1] = gm[a][j * 2 + 1];
    }
  scnt[t] = 0;
  asm volatile("s_waitcnt lgkmcnt(0)" ::: "memory");

  // tau = rank-19 of 32 group maxima (provably <= true 20th score of the chunk)
  for (int r = 0; r < 32; r++) {
    const int q = wave * 64 + r * 2 + (lane >> 5);
    const int idx = lane & 31;
    float v = gmL[q][idx];
#pragma unroll
    for (int kk = 2; kk <= 32; kk <<= 1) {
#pragma unroll
      for (int m = kk >> 1; m >= 1; m >>= 1) {
        float o = shflx_f(v, m);
        bool keepmax = ((idx & kk) == 0) == ((idx & m) == 0);
        v = keepmax ? fmaxf(v, o) : fminf(v, o);
      }
    }
    if (idx == 19) tauL[q] = v;
  }
  asm volatile("s_waitcnt lgkmcnt(0)" ::: "memory");

  float tq[4][4];
#pragma unroll
  for (int a = 0; a < 4; a++)
#pragma unroll
    for (int j = 0; j < 4; j++) tq[a][j] = tauL[wave * 64 + a * 16 + quad * 4 + j];

  // ---- pass 2: bitwise-identical rescore, compact survivors >= tau ----
  ull* slB = slistG + (((size_t)b * NN + qg * 256) * 2 + chunk) * 64;
  loadB(0, 0);
  for (int tt = 0; tt < 64; tt += 2) {
    loadB(1, tt + 1);
    for (int s = 0; s < 2; s++) {
      v4f out[4];
      tile_scores<KB>(s ? Bh[1] : Bh[0], s ? Bl[1] : Bl[0], Ah, Al, xvb[s], out);
      int n = cb + (tt + s) * 16 + col;
#pragma unroll
      for (int a = 0; a < 4; a++)
#pragma unroll
        for (int j = 0; j < 4; j++) {
          float sc = out[a][j];
          if (sc >= tq[a][j]) {
            int qi = wave * 64 + a * 16 + quad * 4 + j;
            int pos = atomicAdd(&scnt[qi], 1);
            if (pos < 64) slB[(size_t)qi * 128 + pos] = packkey(sc, n);
          }
        }
      if (s == 0) loadB(0, tt + 2);
    }
  }
  asm volatile("s_waitcnt lgkmcnt(0)" ::: "memory");
  cntG[((size_t)b * NN + qg * 256 + t) * 2 + chunk] = scnt[t];
}

// ---------------- kNN stage 2: merge 2 chunk survivor lists -> top-20 --------
__global__ __launch_bounds__(256) void knn_merge(const ull* __restrict__ slistG,
    const int* __restrict__ cntG, const _Float16* __restrict__ xh,
    const _Float16* __restrict__ xl, const float* __restrict__ xxg,
    int* __restrict__ idxout, int Cp, int C)
{
  const int lane = threadIdx.x & 63, wave = threadIdx.x >> 6;
  const int b = blockIdx.y;
  const int q = blockIdx.x * 4 + wave;
  const int c0 = cntG[((size_t)b * NN + q) * 2 + 0];
  const int c1 = cntG[((size_t)b * NN + q) * 2 + 1];
  int* op = idxout + ((size_t)b * NN + q) * KK;

  if (c0 <= 64 && c1 <= 64) {
    const ull* s0 = slistG + ((size_t)b * NN + q) * 128;
    const int total = c0 + c1;
    ull e0 = 0, e1 = 0;
    int p0 = lane, p1 = lane + 64;
    if (p0 < total) e0 = (p0 < c0) ? s0[p0] : s0[64 + p0 - c0];
    if (p1 < total) e1 = (p1 < c0) ? s0[p1] : s0[64 + p1 - c0];
    for (int s = 0; s < KK; s++) {
      ull m = e0 > e1 ? e0 : e1;
      ull g = m;
#pragma unroll
      for (int d = 1; d < 64; d <<= 1) { ull o = shflx_u64(g, d); g = o > g ? o : g; }
      if (lane == 0) op[s] = 2047 - (int)(g & 0xFFFFFFFFu);
      if (e0 == g) e0 = 0; else if (e1 == g) e1 = 0;
    }
  } else {
    // exact fallback (survivor cap overflow — expected never): full fp32 rescan
    const _Float16* qh = xh + ((size_t)b * NN + q) * Cp;
    const _Float16* ql = xl + ((size_t)b * NN + q) * Cp;
    const float* xxb = xxg + b * NN;
    float sc[32];
#pragma unroll
    for (int i = 0; i < 32; i++) sc[i] = -0.5f * xxb[lane + 64 * i];
    for (int c = 0; c < C; c++) {
      float qv = (float)qh[c] + (float)ql[c];
      for (int i = 0; i < 32; i++) {
        int n = lane + 64 * i;
        float bv = (float)xh[((size_t)b * NN + n) * Cp + c] + (float)xl[((size_t)b * NN + n) * Cp + c];
        sc[i] = fmaf(qv, bv, sc[i]);
      }
    }
    for (int s = 0; s < KK; s++) {
      ull m = 0; int mi = -1;
      for (int i = 0; i < 32; i++) {
        ull k = packkey(sc[i], lane + 64 * i);
        if (k > m) { m = k; mi = i; }
      }
      ull g = m;
#pragma unroll
      for (int d = 1; d < 64; d <<= 1) { ull o = shflx_u64(g, d); g = o > g ? o : g; }
      if (lane == 0) op[s] = 2047 - (int)(g & 0xFFFFFFFFu);
      if (m == g && mi >= 0) sc[mi] = -3.4e38f;
    }
  }
}

// ---------------- weight converts ----------------
__global__ __launch_bounds__(256) void wcvt_uv(const float* __restrict__ w,
    _Float16* __restrict__ wuh, _Float16* __restrict__ wul,
    _Float16* __restrict__ wvh, _Float16* __restrict__ wvl, int C, int Cp, int O)
{
  int idx = blockIdx.x * 256 + threadIdx.x;
  if (idx >= O * Cp) return;
  int o = idx / Cp, c = idx - o * Cp;
  float a = 0.f, bv = 0.f;
  if (c < C) { a = w[o * 2 * C + c]; bv = w[o * 2 * C + C + c]; }
  float v = bv - a;
  _Float16 ah = (_Float16)a; wuh[idx] = ah; wul[idx] = (_Float16)(a - (float)ah);
  _Float16 vh = (_Float16)v; wvh[idx] = vh; wvl[idx] = (_Float16)(v - (float)vh);
}

__global__ __launch_bounds__(256) void w5cvt(const float* __restrict__ w5,
    _Float16* __restrict__ w5h, _Float16* __restrict__ w5l)
{
  int idx = blockIdx.x * 256 + threadIdx.x;
  float v = w5[idx];
  _Float16 h = (_Float16)v;
  w5h[idx] = h;
  w5l[idx] = (_Float16)(v - (float)h);
}

// ---------------- xcat fp32 [b][c][n] -> f16 hi/lo fragments [b][kc][n][32] ----
__global__ __launch_bounds__(256) void y5cvt_kernel(const float* __restrict__ xcat,
    _Float16* __restrict__ xh, _Float16* __restrict__ xl)
{
  const int b = blockIdx.y;
  const int n = blockIdx.x * 256 + threadIdx.x;
  for (int kc = blockIdx.z * 4; kc < blockIdx.z * 4 + 4; kc++) {
    v8h h[4], l[4];
#pragma unroll
    for (int g = 0; g < 4; g++)
#pragma unroll
      for (int j = 0; j < 8; j++) {
        float v = xcat[((size_t)b * 512 + kc * 32 + g * 8 + j) * NN + n];
        _Float16 hh = (_Float16)v;
        h[g][j] = hh;
        l[g][j] = (_Float16)(v - (float)hh);
      }
    size_t base = (((size_t)b * 16 + kc) * NN + n) * 32;
#pragma unroll
    for (int g = 0; g < 4; g++) {
      *(v8h*)(xh + base + g * 8) = h[g];
      *(v8h*)(xl + base + g * 8) = l[g];
    }
  }
}

// ---------------- y5 = w5 * xcat via MFMA (f16 hi/lo 3-product) ----------------
__global__ __launch_bounds__(256) void y5_mfma(const _Float16* __restrict__ w5h,
    const _Float16* __restrict__ w5l, const _Float16* __restrict__ xh,
    const _Float16* __restrict__ xl, float* __restrict__ y5)
{
  const int lane = threadIdx.x & 63, wave = threadIdx.x >> 6;
  const int col = lane & 15, quad = lane >> 4, quad8 = quad * 8;
  const int b = blockIdx.z;
  const int o0 = blockIdx.x * 256 + wave * 64;
  const int nb0 = blockIdx.y * 128;
  v4f acc[4][8];
#pragma unroll
  for (int a = 0; a < 4; a++)
#pragma unroll
    for (int t = 0; t < 8; t++) acc[a][t] = {0.f, 0.f, 0.f, 0.f};

  for (int kc = 0; kc < 16; kc++) {
    v8h Ah[4], Al[4];
#pragma unroll
    for (int a = 0; a < 4; a++) {
      size_t off = (size_t)(o0 + a * 16 + col) * 512 + kc * 32 + quad8;
      Ah[a] = *(const v8h*)(w5h + off);
      Al[a] = *(const v8h*)(w5l + off);
    }
#pragma unroll
    for (int t = 0; t < 8; t++) {
      int n = nb0 + t * 16 + col;
      size_t boff = (((size_t)b * 16 + kc) * NN + n) * 32 + quad8;
      v8h Bh = *(const v8h*)(xh + boff);
      v8h Bl = *(const v8h*)(xl + boff);
#pragma unroll
      for (int a = 0; a < 4; a++) {
        acc[a][t] = __builtin_amdgcn_mfma_f32_16x16x32_f16(Ah[a], Bh, acc[a][t], 0, 0, 0);
        acc[a][t] = __builtin_amdgcn_mfma_f32_16x16x32_f16(Ah[a], Bl, acc[a][t], 0, 0, 0);
        acc[a][t] = __builtin_amdgcn_mfma_f32_16x16x32_f16(Al[a], Bh, acc[a][t], 0, 0, 0);
      }
    }
  }
#pragma unroll
  for (int a = 0; a < 4; a++)
#pragma unroll
    for (int t = 0; t < 8; t++)
#pragma unroll
      for (int j = 0; j < 4; j++)
        y5[((size_t)b * 512 + o0 + a * 16 + quad * 4 + j) * NN + nb0 + t * 16 + col] = acc[a][t][j];
}

// ---------------- U/V chunk (up to 128 out-ch) via MFMA, 4 n-tiles/wave --------
__global__ __launch_bounds__(256) void uv_mfma(const _Float16* __restrict__ wuh,
    const _Float16* __restrict__ wul, const _Float16* __restrict__ wvh,
    const _Float16* __restrict__ wvl, const _Float16* __restrict__ xh,
    const _Float16* __restrict__ xl, float* __restrict__ Uc, float* __restrict__ Vc,
    int Cp, int Och)
{
  const int lane = threadIdx.x & 63, wave = threadIdx.x >> 6;
  const int col = lane & 15, quad = lane >> 4, quad8 = quad * 8;
  const int b = blockIdx.z;
  const int o0 = blockIdx.x * 32;           // chunk-local out channel base
  const int nb0 = blockIdx.y * 256 + wave * 64;
  v4f aU[2][4], aV[2][4];
#pragma unroll
  for (int a = 0; a < 2; a++)
#pragma unroll
    for (int t = 0; t < 4; t++) { aU[a][t] = {0.f,0.f,0.f,0.f}; aV[a][t] = {0.f,0.f,0.f,0.f}; }

  const int KBr = Cp >> 5;
  for (int kb = 0; kb < KBr; kb++) {
    v8h Uh[2], Ul[2], Vh[2], Vl[2];
#pragma unroll
    for (int a = 0; a < 2; a++) {
      size_t off = (size_t)(o0 + a * 16 + col) * Cp + kb * 32 + quad8;
      Uh[a] = *(const v8h*)(wuh + off);
      Ul[a] = *(const v8h*)(wul + off);
      Vh[a] = *(const v8h*)(wvh + off);
      Vl[a] = *(const v8h*)(wvl + off);
    }
#pragma unroll
    for (int t = 0; t < 4; t++) {
      int n = nb0 + t * 16 + col;
      size_t boff = ((size_t)b * NN + n) * Cp + kb * 32 + quad8;
      v8h Bh = *(const v8h*)(xh + boff);
      v8h Bl = *(const v8h*)(xl + boff);
#pragma unroll
      for (int a = 0; a < 2; a++) {
        aU[a][t] = __builtin_amdgcn_mfma_f32_16x16x32_f16(Uh[a], Bh, aU[a][t], 0, 0, 0);
        aU[a][t] = __builtin_amdgcn_mfma_f32_16x16x32_f16(Uh[a], Bl, aU[a][t], 0, 0, 0);
        aU[a][t] = __builtin_amdgcn_mfma_f32_16x16x32_f16(Ul[a], Bh, aU[a][t], 0, 0, 0);
        aV[a][t] = __builtin_amdgcn_mfma_f32_16x16x32_f16(Vh[a], Bh, aV[a][t], 0, 0, 0);
        aV[a][t] = __builtin_amdgcn_mfma_f32_16x16x32_f16(Vh[a], Bl, aV[a][t], 0, 0, 0);
        aV[a][t] = __builtin_amdgcn_mfma_f32_16x16x32_f16(Vl[a], Bh, aV[a][t], 0, 0, 0);
      }
    }
  }
#pragma unroll
  for (int a = 0; a < 2; a++)
#pragma unroll
    for (int t = 0; t < 4; t++)
#pragma unroll
      for (int j = 0; j < 4; j++) {
        size_t base = ((size_t)b * Och + o0 + a * 16 + quad * 4 + j) * NN + nb0 + t * 16 + col;
        Uc[base] = aU[a][t][j];
        Vc[base] = aV[a][t][j];
      }
}

// ---------------- edge5: 2 channels/block, 2-pass, 2-4 blocks/CU ---------------
// Uc/Vc are chunk-local [b][Och][NN]; xo pre-offset to the chunk's first channel.
__global__ __launch_bounds__(256) void edge5(const float* __restrict__ Uc,
    const float* __restrict__ Vc, const int* __restrict__ idx,
    float* __restrict__ xo, int Och)
{
  __shared__ float Ur[2 * 2052];   // +4 pad breaks power-of-2 collisions
  __shared__ float red[4][4];
  __shared__ float smv[4];
  const int b = blockIdx.y, o0 = blockIdx.x * 2;
  const int t = threadIdx.x, lane = t & 63, wave = t >> 6;
  for (int r = 0; r < 2; r++)
    for (int i = t; i < NN; i += 256)
      Ur[r * 2052 + i] = Uc[((size_t)b * Och + o0 + r) * NN + i];
  __syncthreads();
  const float* Vp = Vc + ((size_t)b * Och + o0) * NN;
  const int* ib = idx + (size_t)b * NN * KK;
  float s0 = 0, s1 = 0, c0 = 0, c1 = 0;
  for (int n = t; n < NN; n += 256) {
    float v0 = Vp[n], v1 = Vp[NN + n];
    const int* ip = ib + (size_t)n * KK;
#pragma unroll
    for (int j = 0; j < KK; j++) {
      int m = ip[j];
      float y0 = Ur[m] + v0, y1 = Ur[2052 + m] + v1;
      s0 += y0; c0 = fmaf(y0, y0, c0);
      s1 += y1; c1 = fmaf(y1, y1, c1);
    }
  }
  float st[4] = { s0, s1, c0, c1 };
#pragma unroll
  for (int k = 0; k < 4; k++) {
    float a = st[k];
#pragma unroll
    for (int d = 1; d < 64; d <<= 1) a += shflx_f(a, d);
    if (lane == 0) red[k][wave] = a;
  }
  __syncthreads();
  if (t < 2) {
    float a = red[t][0] + red[t][1] + red[t][2] + red[t][3];
    float c = red[2 + t][0] + red[2 + t][1] + red[2 + t][2] + red[2 + t][3];
    const float inv = 1.f / (float)(NN * KK);
    float mu = a * inv;
    float var = fmaxf(c * inv - mu * mu, 0.f);
    smv[t] = mu;
    smv[2 + t] = rsqrtf(var + EPSF);
  }
  __syncthreads();
  const float mu0 = smv[0], mu1 = smv[1], i0 = smv[2], i1 = smv[3];
  for (int n = t; n < NN; n += 256) {
    float v0 = Vp[n], v1 = Vp[NN + n];
    const int* ip = ib + (size_t)n * KK;
    float m0 = -3.4e38f, m1 = m0;
#pragma unroll
    for (int j = 0; j < KK; j++) {
      int m = ip[j];
      m0 = fmaxf(m0, Ur[m] + v0);
      m1 = fmaxf(m1, Ur[2052 + m] + v1);
    }
    float z;  // leaky-relu commutes with max (i > 0)
    z = (m0 - mu0) * i0; xo[((size_t)b * 512 + o0 + 0) * NN + n] = z >= 0.f ? z : 0.2f * z;
    z = (m1 - mu1) * i1; xo[((size_t)b * 512 + o0 + 1) * NN + n] = z >= 0.f ? z : 0.2f * z;
  }
}

__global__ __launch_bounds__(256) void bn5stat_kernel(const float* __restrict__ y5,
    float* __restrict__ bn5) {
  __shared__ float rs[4], rq[4];
  const int o = blockIdx.x, t = threadIdx.x, lane = t & 63, wave = t >> 6;
  float s = 0.f, q = 0.f;
  for (int b = 0; b < NB; b++) {
    const float* p = y5 + ((size_t)b * 512 + o) * NN;
    for (int n = t; n < NN; n += 256) { float v = p[n]; s += v; q = fmaf(v, v, q); }
  }
#pragma unroll
  for (int d = 1; d < 64; d <<= 1) { s += shflx_f(s, d); q += shflx_f(q, d); }
  if (lane == 0) { rs[wave] = s; rq[wave] = q; }
  __syncthreads();
  if (t == 0) {
    float S = rs[0] + rs[1] + rs[2] + rs[3];
    float Q = rq[0] + rq[1] + rq[2] + rq[3];
    const float inv = 1.f / (float)(NB * NN);
    float mu = S * inv;
    float var = fmaxf(Q * inv - mu * mu, 0.f);
    bn5[o] = mu;
    bn5[512 + o] = rsqrtf(var + EPSF);
  }
}

__global__ __launch_bounds__(256) void final_kernel(const float* __restrict__ y5,
    const float* __restrict__ bn5, const float* __restrict__ gamma,
    const float* __restrict__ beta, float* __restrict__ out)
{
  __shared__ float rm[4], rs[4];
  const int o = blockIdx.x, b = blockIdx.y, t = threadIdx.x, lane = t & 63, wave = t >> 6;
  const float mu = bn5[o], iv = bn5[512 + o], g = gamma[o], be = beta[o];
  const float* p = y5 + ((size_t)b * 512 + o) * NN;
  float mx = -3.4e38f, sm = 0.f;
  for (int n = t; n < NN; n += 256) {
    float z = (p[n] - mu) * iv;
    z = z * g + be;
    z = (z >= 0.f) ? z : 0.2f * z;
    mx = fmaxf(mx, z);
    sm += z;
  }
#pragma unroll
  for (int d = 1; d < 64; d <<= 1) { mx = fmaxf(mx, shflx_f(mx, d)); sm += shflx_f(sm, d); }
  if (lane == 0) { rm[wave] = mx; rs[wave] = sm; }
  __syncthreads();
  if (t == 0) {
    float M = fmaxf(fmaxf(rm[0], rm[1]), fmaxf(rm[2], rm[3]));
    float S = rs[0] + rs[1] + rs[2] + rs[3];
    out[(size_t)b * 1024 + o] = M;
    out[(size_t)b * 1024 + 512 + o] = S * (1.f / NN);
  }
}

extern "C" void kernel_launch(void* const* d_in, const int* in_sizes, int n_in,
                              void* d_out, int out_size, void* d_ws, size_t ws_size,
                              hipStream_t stream)
{
  (void)in_sizes; (void)n_in; (void)out_size; (void)ws_size;
  const float* x  = (const float*)d_in[0];
  const float* w1 = (const float*)d_in[1];
  const float* w2 = (const float*)d_in[2];
  const float* w3 = (const float*)d_in[3];
  const float* w4 = (const float*)d_in[4];
  const float* w5 = (const float*)d_in[5];
  const float* g5 = (const float*)d_in[6];
  const float* b5 = (const float*)d_in[7];
  float* out = (float*)d_out;

  // workspace layout (same 137 MB footprint)
  float* ws   = (float*)d_ws;
  float* xcat = ws;                         // 16*512*2048 fp32 (67.1 MB)
  float* Ub   = xcat + 16777216;            // 8.39M floats (33.5 MB)
  float* Vb   = Ub + 8388608;               // 8.39M floats (33.5 MB)
  int*   idxb = (int*)(Vb + 8388608);       // 16*2048*20 ints
  float* xxb  = (float*)(idxb + 655360);    // 32768 floats
  float* bn5  = xxb + 32768;                // 1024

  // Vb carve-up: xth | xtl | cntb | weight stash
  _Float16* xth = (_Float16*)Vb;                       // 4.19M halves
  _Float16* xtl = xth + 4194304;                       // 4.19M halves
  int* cntb = (int*)(Vb + 4194304);                    // 65536 ints
  _Float16* wuh = (_Float16*)(Vb + 4259840);           // 4 x 32768 halves
  _Float16* wul = wuh + 32768;
  _Float16* wvh = wul + 32768;
  _Float16* wvl = wvh + 32768;

  ull* slist = (ull*)Ub;       // survivor lists alias Ub (dead after merge)
  float* Uc = Ub;              // chunk U (up to 128ch = 4.19M floats)
  float* Vc = Ub + 4194304;    // chunk V (up to 128ch)

  _Float16* w5h = (_Float16*)idxb;   // idx dead after last edge
  _Float16* w5l = w5h + 262144;
  _Float16* xcfh = (_Float16*)Ub;
  _Float16* xcfl = (_Float16*)Vb;
  float* y5 = xcat;

  struct Lyr { const float* xin; long bstride; int C, KB, O, coff; const float* w; };
  const Lyr L[4] = {
    { x,              3L * NN,   3,   1, 64,  0,   w1 },
    { xcat,           512L * NN, 64,  2, 64,  64,  w2 },
    { xcat + 64 * NN, 512L * NN, 64,  2, 128, 128, w3 },
    { xcat + 128 * NN,512L * NN, 128, 4, 256, 256, w4 },
  };

  for (int l = 0; l < 4; l++) {
    const int Cp = L[l].KB * 32, O = L[l].O, C = L[l].C;
    prep_kernel<<<dim3(NN / 256, NB), 256, 0, stream>>>(L[l].xin, xth, xtl, xxb,
                                                        C, L[l].KB, L[l].bstride);
    switch (L[l].KB) {
      case 1: knn2<1><<<dim3(NB * 2, NN / 256), 256, 0, stream>>>(xth, xtl, xxb, slist, cntb); break;
      case 2: knn2<2><<<dim3(NB * 2, NN / 256), 256, 0, stream>>>(xth, xtl, xxb, slist, cntb); break;
      default: knn2<4><<<dim3(NB * 2, NN / 256), 256, 0, stream>>>(xth, xtl, xxb, slist, cntb); break;
    }
    knn_merge<<<dim3(NN / 4, NB), 256, 0, stream>>>(slist, cntb, xth, xtl, xxb, idxb,
                                                    Cp, C);
    wcvt_uv<<<(O * Cp + 255) / 256, 256, 0, stream>>>(L[l].w, wuh, wul, wvh, wvl,
                                                      C, Cp, O);
    for (int c0 = 0; c0 < O; c0 += 128) {
      const int Och = (O - c0) < 128 ? (O - c0) : 128;
      uv_mfma<<<dim3(Och / 32, NN / 256, NB), 256, 0, stream>>>(
          wuh + (size_t)c0 * Cp, wul + (size_t)c0 * Cp,
          wvh + (size_t)c0 * Cp, wvl + (size_t)c0 * Cp,
          xth, xtl, Uc, Vc, Cp, Och);
      edge5<<<dim3(Och / 2, NB), 256, 0, stream>>>(Uc, Vc, idxb,
          xcat + (size_t)(L[l].coff + c0) * NN, Och);
    }
  }
  w5cvt<<<1024, 256, 0, stream>>>(w5, w5h, w5l);
  y5cvt_kernel<<<dim3(NN / 256, NB, 4), 256, 0, stream>>>(xcat, xcfh, xcfl);
  y5_mfma<<<dim3(2, NN / 128, NB), 256, 0, stream>>>(w5h, w5l, xcfh, xcfl, y5);
  bn5stat_kernel<<<512, 256, 0, stream>>>(y5, bn5);
  final_kernel<<<dim3(512, NB), 256, 0, stream>>>(y5, bn5, g5, b5, out);
}